// Round 5
// baseline (361.637 us; speedup 1.0000x reference)
//
#include <hip/hip_runtime.h>

// GCN link predictor: z1 = relu(GCNConv(x,W1,b1)); z2 = GCNConv(z1,W2,b2);
// out[e] = dot(z2[src[e]], z2[dst[e]])
// R9: full bf16 data plane, bf16 MFMA GEMM (hi/lo split for accuracy).
// R10: 50us gemm — W loads sunk into loop (VGPR=52), L2 refetch/step.
// R11 FAILED: reg-W + reg dbuf -> spill (VGPR=80), gemm 130us.
// R12/R13 FAILED: 64KB LDS-W + 256 rows/block -> grid=391, occ 11%, 79us.
// R14 FAILED: 32-VGPR reg-W, grid 3126 -> compiler SANK B loads again
//      (VGPR=44): const __restrict__ global loads are rematerializable and
//      the allocator refuses to carry them across any loop. occ 40%, 69us,
//      FETCH 2x (cg split re-reads A).
// LESSON: W must live in LDS (unsinkable); occupancy must come from grid.
// R15: 512-thr block (8 waves), 64 rows x 128 cols, W hi+lo in 64KB LDS.
//      Wave = one col-tile; 8 ds_read + 8 MFMA per m-tile; 4 m-tiles.
//      Grid ceil(M/64)=1563, 2 blocks/CU (LDS-capped) = 16 waves/CU.
//      No cg split -> A read once (FETCH back to ideal).

typedef __attribute__((ext_vector_type(8))) short short8;  // 8 bf16 = 4 VGPRs
typedef __attribute__((ext_vector_type(4))) float f32x4;

__device__ __forceinline__ unsigned bf16_rne(float x) {
  unsigned u = __builtin_bit_cast(unsigned, x);
  return (u + 0x7FFFu + ((u >> 16) & 1u)) >> 16;
}
__device__ __forceinline__ float bf2f(unsigned short u) {
  return __builtin_bit_cast(float, ((unsigned)u) << 16);
}

// ---------- degree: 4 edges/thread ----------
__global__ __launch_bounds__(256) void deg_kernel(const int* __restrict__ dst,
                                                  int* __restrict__ deg, int E) {
  int base = blockIdx.x * 1024 + threadIdx.x;
#pragma unroll
  for (int i = 0; i < 4; ++i) {
    int e = base + i * 256;
    if (e < E) atomicAdd(&deg[dst[e]], 1);
  }
}

// ---------- block scan (512 elems/block) ----------
__global__ __launch_bounds__(512) void scan1_kernel(const int* __restrict__ in,
                                                    int* __restrict__ tmp,
                                                    int* __restrict__ bsums, int n) {
  __shared__ int sm[2][512];
  int t = threadIdx.x;
  int gid = blockIdx.x * 512 + t;
  int v = (gid < n) ? in[gid] : 0;
  int pp = 0;
  sm[0][t] = v;
  __syncthreads();
  for (int off = 1; off < 512; off <<= 1) {
    int nv = sm[pp][t];
    if (t >= off) nv += sm[pp][t - off];
    sm[pp ^ 1][t] = nv;
    pp ^= 1;
    __syncthreads();
  }
  int inc = sm[pp][t];
  if (gid < n) tmp[gid] = inc;
  if (t == 511) bsums[blockIdx.x] = inc;
}

__global__ __launch_bounds__(256) void scan2_kernel(int* bsums, int nb) {
  __shared__ int sm[2][256];
  int t = threadIdx.x;
  int v = (t < nb) ? bsums[t] : 0;
  int pp = 0;
  sm[0][t] = v;
  __syncthreads();
  for (int off = 1; off < 256; off <<= 1) {
    int nv = sm[pp][t];
    if (t >= off) nv += sm[pp][t - off];
    sm[pp ^ 1][t] = nv;
    pp ^= 1;
    __syncthreads();
  }
  int inc = sm[pp][t];
  if (t < nb) bsums[t] = inc - v;  // exclusive
}

// rowptr from scan, plus dinv = rsqrt(deg+1) fused here
__global__ __launch_bounds__(256) void scan3_kernel(const int* __restrict__ tmp,
                                                    const int* __restrict__ bsums,
                                                    const int* __restrict__ deg,
                                                    int* __restrict__ rowptr,
                                                    float* __restrict__ dinv, int n) {
  int gid = blockIdx.x * 256 + threadIdx.x;
  if (gid < n) {
    rowptr[gid + 1] = tmp[gid] + bsums[gid >> 9];
    dinv[gid] = rsqrtf((float)(deg[gid] + 1));  // +1 self loop
  }
  if (gid == 0) rowptr[0] = 0;
}

// CSR scatter: one int2 {src, eid} store per edge; 4 edges/thread for MLP.
__global__ __launch_bounds__(256) void scatter_kernel(const int* __restrict__ src,
                                                      const int* __restrict__ dst,
                                                      const int* __restrict__ rowptr,
                                                      int* __restrict__ cnt,
                                                      int2* __restrict__ csr, int E) {
  int base = blockIdx.x * 1024 + threadIdx.x;
#pragma unroll
  for (int i = 0; i < 4; ++i) {
    int e = base + i * 256;
    if (e < E) {
      int d = dst[e];
      int pos = rowptr[d] + atomicAdd(&cnt[d], 1);
      csr[pos] = make_int2(src[e], e);
    }
  }
}

// ---------- pack W[128][128] fp32 -> bf16 hi/lo in MFMA B-fragment order ----
// B frag (16x16x32): lane holds B[k=(lane>>4)*8+j][n=lane&15], j=0..7.
// Layout: Wp[half(0=hi,1=lo)][ct(8)][kf(4)][lane(64)][8] bf16.
__global__ __launch_bounds__(256) void wpack_kernel(const float* __restrict__ W,
                                                    short* __restrict__ Wp) {
  int t = blockIdx.x * 256 + threadIdx.x;  // 2048 = ct*256 + kf*64 + lane
  if (t >= 2048) return;
  int lane = t & 63;
  int kf = (t >> 6) & 3;
  int ct = t >> 8;
  int col = ct * 16 + (lane & 15);
  int k0 = kf * 32 + (lane >> 4) * 8;
  short* dh = Wp + ((((0 * 8 + ct) * 4 + kf) * 64) + lane) * 8;
  short* dl = Wp + ((((1 * 8 + ct) * 4 + kf) * 64) + lane) * 8;
  for (int j = 0; j < 8; ++j) {
    float w = W[(k0 + j) * 128 + col];
    unsigned h = bf16_rne(w);
    float hf = __builtin_bit_cast(float, h << 16);
    unsigned lo = bf16_rne(w - hf);
    dh[j] = (short)h;
    dl[j] = (short)lo;
  }
}

// ---------- bf16 MFMA GEMM: out[r,:] = bf16( dinv[r] * (A[r,:] @ W) ) ----
// FP32A=true: A is fp32, converted to bf16 in-register (layer 1, reads x).
// FP32A=false: A is bf16 (layer 2). W split hi/lo.
// R15 structure: 512 threads = 8 waves; wave owns one 16-col tile (ct=wave).
// W hi+lo (64KB packed) staged once into LDS; ds_read_b128 B-frags feed
// MFMAs directly (compiler cannot sink LDS). 64 rows/block as 4 m-tiles,
// '#pragma unroll 1'. Grid ceil(M/64); 2 blocks/CU (LDS) = 16 waves/CU.
template <bool FP32A>
__global__ __launch_bounds__(512, 4) void gemm_kernel(const void* __restrict__ Av,
                                                      const short* __restrict__ Wp,
                                                      const float* __restrict__ dinv,
                                                      unsigned short* __restrict__ out,
                                                      int M) {
  __shared__ short8 lds_w[4096];  // 64 KB: [half][ct8][kf4][lane64], 16B units

  const int tid = threadIdx.x;
  // stage packed W: 4096 x 16B chunks, 512 threads -> 8 iters (L2-broadcast)
  {
    const short8* Wg = (const short8*)Wp;
#pragma unroll
    for (int i = 0; i < 8; ++i) lds_w[i * 512 + tid] = Wg[i * 512 + tid];
  }
  __syncthreads();

  const int wave = tid >> 6;  // 0..7 = this wave's col-tile
  const int lane = tid & 63;
  const int quad = lane >> 4;
  const int l15 = lane & 15;
  const int ct = wave;
  const int colbase = ct * 16 + l15;
  const short8* WL = lds_w;

  const int rb0 = blockIdx.x * 64;
  const short8 s8z = {0, 0, 0, 0, 0, 0, 0, 0};

#pragma unroll 1
  for (int mt = 0; mt < 4; ++mt) {
    const int rb = rb0 + mt * 16;
    if (rb >= M) break;

    // A fragments: lane holds A[m=l15][k=f*32+quad*8+j]
    const int arow = rb + l15;
    const bool rok = arow < M;
    short8 af[4];
    if constexpr (FP32A) {
      const float4* A4 = (const float4*)Av + (size_t)arow * 32;
#pragma unroll
      for (int f = 0; f < 4; ++f) {
        if (rok) {
          float4 a0 = A4[f * 8 + quad * 2];
          float4 a1 = A4[f * 8 + quad * 2 + 1];
          float av[8] = {a0.x, a0.y, a0.z, a0.w, a1.x, a1.y, a1.z, a1.w};
#pragma unroll
          for (int j = 0; j < 8; ++j) af[f][j] = (short)bf16_rne(av[j]);
        } else {
          af[f] = s8z;
        }
      }
    } else {
      const unsigned short* A2 = (const unsigned short*)Av + (size_t)arow * 128;
#pragma unroll
      for (int f = 0; f < 4; ++f)
        af[f] = rok ? *(const short8*)(A2 + f * 32 + quad * 8) : s8z;
    }

    f32x4 acc = {0.f, 0.f, 0.f, 0.f};
#pragma unroll
    for (int f = 0; f < 4; ++f) {
      short8 bh = WL[((0 * 8 + ct) * 4 + f) * 64 + lane];
      short8 bl = WL[((1 * 8 + ct) * 4 + f) * 64 + lane];
      acc = __builtin_amdgcn_mfma_f32_16x16x32_bf16(af[f], bh, acc, 0, 0, 0);
      acc = __builtin_amdgcn_mfma_f32_16x16x32_bf16(af[f], bl, acc, 0, 0, 0);
    }

    // epilogue: C/D layout col=lane&15, row=quad*4+i
#pragma unroll
    for (int i = 0; i < 4; ++i) {
      const int r = rb + quad * 4 + i;
      if (r < M) {
        const float d = dinv[r];
        out[(size_t)r * 128 + colbase] = (unsigned short)bf16_rne(acc[i] * d);
      }
    }
  }
}

// ---------- aggregation over prescaled bf16 rows ----------
// out[i] = bf16( dinv[i]*(xw[i] + sum_j xw[j]) + b ), fp32 accumulation.
// 16 lanes/node, one ushort8 (16B) per lane per row, neighbor unroll x4.
__global__ __launch_bounds__(256) void agg_kernel(const unsigned short* __restrict__ xw,
                                                  const float* __restrict__ dinv,
                                                  const int* __restrict__ rowptr,
                                                  const int2* __restrict__ csr,
                                                  const float* __restrict__ bias,
                                                  unsigned short* __restrict__ out,
                                                  int relu, int N) {
  int node = blockIdx.x * 16 + (threadIdx.x >> 4);
  int l = threadIdx.x & 15;
  if (node >= N) return;
  const short8* xw8 = (const short8*)xw;  // row = 16 short8 groups
  short8 sv = xw8[(size_t)node * 16 + l];
  float acc[8];
#pragma unroll
  for (int j = 0; j < 8; ++j) acc[j] = bf2f((unsigned short)sv[j]);
  int s = rowptr[node], e = rowptr[node + 1];
  int k = s;
  for (; k + 4 <= e; k += 4) {
    int j0 = csr[k].x, j1 = csr[k + 1].x, j2 = csr[k + 2].x, j3 = csr[k + 3].x;
    short8 v0 = xw8[(size_t)j0 * 16 + l];
    short8 v1 = xw8[(size_t)j1 * 16 + l];
    short8 v2 = xw8[(size_t)j2 * 16 + l];
    short8 v3 = xw8[(size_t)j3 * 16 + l];
#pragma unroll
    for (int j = 0; j < 8; ++j) {
      acc[j] += (bf2f((unsigned short)v0[j]) + bf2f((unsigned short)v1[j])) +
                (bf2f((unsigned short)v2[j]) + bf2f((unsigned short)v3[j]));
    }
  }
  for (; k < e; ++k) {
    short8 v = xw8[(size_t)csr[k].x * 16 + l];
#pragma unroll
    for (int j = 0; j < 8; ++j) acc[j] += bf2f((unsigned short)v[j]);
  }
  float di = dinv[node];
  const float4* b4 = (const float4*)bias;
  float4 bb0 = b4[l * 2], bb1 = b4[l * 2 + 1];
  float bv[8] = {bb0.x, bb0.y, bb0.z, bb0.w, bb1.x, bb1.y, bb1.z, bb1.w};
  short8 o;
#pragma unroll
  for (int j = 0; j < 8; ++j) {
    float v = fmaf(di, acc[j], bv[j]);
    if (relu) v = fmaxf(v, 0.f);
    o[j] = (short)bf16_rne(v);
  }
  ((short8*)out)[(size_t)node * 16 + l] = o;
}

// ---------- decode over dst-CSR, bf16 z2: 16 lanes/node ----------
__global__ __launch_bounds__(256) void decode_kernel(const unsigned short* __restrict__ z,
                                                     const int* __restrict__ rowptr,
                                                     const int2* __restrict__ csr,
                                                     float* __restrict__ out, int N) {
  int node = blockIdx.x * 16 + (threadIdx.x >> 4);
  int l = threadIdx.x & 15;
  if (node >= N) return;
  const short8* z8 = (const short8*)z;
  short8 zv = z8[(size_t)node * 16 + l];
  float zd[8];
#pragma unroll
  for (int j = 0; j < 8; ++j) zd[j] = bf2f((unsigned short)zv[j]);
  int s = rowptr[node], e = rowptr[node + 1];
  int k = s;
  for (; k + 4 <= e; k += 4) {
    int2 c0 = csr[k], c1 = csr[k + 1], c2 = csr[k + 2], c3 = csr[k + 3];
    short8 v0 = z8[(size_t)c0.x * 16 + l];
    short8 v1 = z8[(size_t)c1.x * 16 + l];
    short8 v2 = z8[(size_t)c2.x * 16 + l];
    short8 v3 = z8[(size_t)c3.x * 16 + l];
    float p0 = 0.f, p1 = 0.f, p2 = 0.f, p3 = 0.f;
#pragma unroll
    for (int j = 0; j < 8; ++j) {
      p0 = fmaf(zd[j], bf2f((unsigned short)v0[j]), p0);
      p1 = fmaf(zd[j], bf2f((unsigned short)v1[j]), p1);
      p2 = fmaf(zd[j], bf2f((unsigned short)v2[j]), p2);
      p3 = fmaf(zd[j], bf2f((unsigned short)v3[j]), p3);
    }
#pragma unroll
    for (int off = 8; off > 0; off >>= 1) {
      p0 += __shfl_xor(p0, off);
      p1 += __shfl_xor(p1, off);
      p2 += __shfl_xor(p2, off);
      p3 += __shfl_xor(p3, off);
    }
    if (l == 0) {
      out[c0.y] = p0;
      out[c1.y] = p1;
      out[c2.y] = p2;
      out[c3.y] = p3;
    }
  }
  for (; k < e; ++k) {
    int2 c = csr[k];
    short8 v = z8[(size_t)c.x * 16 + l];
    float p = 0.f;
#pragma unroll
    for (int j = 0; j < 8; ++j) p = fmaf(zd[j], bf2f((unsigned short)v[j]), p);
#pragma unroll
    for (int off = 8; off > 0; off >>= 1) p += __shfl_xor(p, off);
    if (l == 0) out[c.y] = p;
  }
}

extern "C" void kernel_launch(void* const* d_in, const int* in_sizes, int n_in,
                              void* d_out, int out_size, void* d_ws, size_t ws_size,
                              hipStream_t stream) {
  const float* x  = (const float*)d_in[0];
  const int*   ei = (const int*)d_in[1];
  const float* W1 = (const float*)d_in[2];
  const float* b1 = (const float*)d_in[3];
  const float* W2 = (const float*)d_in[4];
  const float* b2 = (const float*)d_in[5];

  const int N = in_sizes[0] / 128;
  const int E = in_sizes[1] / 2;
  const int* src = ei;
  const int* dst = ei + E;

  char* ws = (char*)d_ws;
  size_t off = 0;
  auto alloc = [&](size_t bytes) -> void* {
    void* p = ws + off;
    off += (bytes + 255) & ~(size_t)255;
    return p;
  };
  unsigned short* bufA = (unsigned short*)alloc((size_t)N * 128 * 2);
  unsigned short* bufB = (unsigned short*)alloc((size_t)N * 128 * 2);
  float* dinv    = (float*)alloc((size_t)N * 4);
  int*   rowptr  = (int*)alloc((size_t)(N + 1) * 4);
  int2*  csr     = (int2*)alloc((size_t)E * 8);
  short* Wp1     = (short*)alloc((size_t)2 * 8 * 4 * 64 * 8 * 2);
  short* Wp2     = (short*)alloc((size_t)2 * 8 * 4 * 64 * 8 * 2);
  int*   tmp     = (int*)alloc((size_t)N * 4);
  int*   deg     = (int*)alloc((size_t)N * 4);   // zeroed region starts here
  int*   cnt     = (int*)alloc((size_t)N * 4);
  int*   bsums   = (int*)alloc(1024);
  size_t zbytes = ((char*)bsums + 1024) - (char*)deg;
  hipMemsetAsync(deg, 0, zbytes, stream);

  const int E4B = (E + 1023) / 1024;
  const int NB = (N + 255) / 256;
  const int SB = (N + 511) / 512;

  // W packing (independent of graph prep)
  wpack_kernel<<<8, 256, 0, stream>>>(W1, Wp1);
  wpack_kernel<<<8, 256, 0, stream>>>(W2, Wp2);

  deg_kernel<<<E4B, 256, 0, stream>>>(dst, deg, E);
  scan1_kernel<<<SB, 512, 0, stream>>>(deg, tmp, bsums, N);
  scan2_kernel<<<1, 256, 0, stream>>>(bsums, SB);
  scan3_kernel<<<NB, 256, 0, stream>>>(tmp, bsums, deg, rowptr, dinv, N);
  scatter_kernel<<<E4B, 256, 0, stream>>>(src, dst, rowptr, cnt, csr, E);

  const int GB = (N + 63) / 64;
  const int AB = (N + 15) / 16;
  const int DB = (N + 15) / 16;

  // layer 1 (A = x, fp32 -> bf16 in-register)
  gemm_kernel<true><<<GB, 512, 0, stream>>>(x, Wp1, dinv, bufA, N);
  agg_kernel<<<AB, 256, 0, stream>>>(bufA, dinv, rowptr, csr, b1, bufB, 1, N);
  // layer 2 (A = z1, bf16)
  gemm_kernel<false><<<GB, 512, 0, stream>>>(bufB, Wp2, dinv, bufA, N);
  agg_kernel<<<AB, 256, 0, stream>>>(bufA, dinv, rowptr, csr, b2, bufB, 0, N);
  // decode over dst-CSR
  decode_kernel<<<DB, 256, 0, stream>>>(bufB, rowptr, csr, (float*)d_out, N);
}

// Round 6
// 339.012 us; speedup vs baseline: 1.0667x; 1.0667x over previous
//
#include <hip/hip_runtime.h>

// GCN link predictor: z1 = relu(GCNConv(x,W1,b1)); z2 = GCNConv(z1,W2,b2);
// out[e] = dot(z2[src[e]], z2[dst[e]])
// R9: full bf16 data plane, bf16 MFMA GEMM (hi/lo split for accuracy).
// R10: 50us gemm — best so far. W re-fetched from L2 per m-tile (sunk).
// R11 FAILED: reg-W + reg dbuf -> spill, 130us.
// R12/R13 FAILED: 64KB LDS-W big blocks -> occ 11%, 79us.
// R14: 1 ct/wave reg-W attempt -> W sunk again (VGPR 44), 69us, occ 40%.
// R15 FAILED: LDS-W 512t -> 75us. LDS/W-residency is NOT the lever; W-from-L2
//      is fine (R10 fastest while re-fetching W every m-tile from L2).
// DIAGNOSIS: every variant serializes per m-tile: A-load -> vmcnt -> convert
//      -> 8-deep MFMA chain -> store. agg/decode (more bytes, random gather)
//      are faster because they keep independent loads in flight continuously.
// R16: R14 skeleton (no LDS, no barrier, 256t, cg split) + straight-line
//      4-stage body (nothing to sink into), A-prefetch depth 1 (t+1 loads
//      issue before t's MFMAs), split hi/lo accumulator chains, block-uniform
//      bounds (fast path has zero predicates), launch_bounds(256,4).

typedef __attribute__((ext_vector_type(8))) short short8;  // 8 bf16 = 4 VGPRs
typedef __attribute__((ext_vector_type(4))) float f32x4;

__device__ __forceinline__ unsigned bf16_rne(float x) {
  unsigned u = __builtin_bit_cast(unsigned, x);
  return (u + 0x7FFFu + ((u >> 16) & 1u)) >> 16;
}
__device__ __forceinline__ float bf2f(unsigned short u) {
  return __builtin_bit_cast(float, ((unsigned)u) << 16);
}

// ---------- degree: 4 edges/thread ----------
__global__ __launch_bounds__(256) void deg_kernel(const int* __restrict__ dst,
                                                  int* __restrict__ deg, int E) {
  int base = blockIdx.x * 1024 + threadIdx.x;
#pragma unroll
  for (int i = 0; i < 4; ++i) {
    int e = base + i * 256;
    if (e < E) atomicAdd(&deg[dst[e]], 1);
  }
}

// ---------- block scan (512 elems/block) ----------
__global__ __launch_bounds__(512) void scan1_kernel(const int* __restrict__ in,
                                                    int* __restrict__ tmp,
                                                    int* __restrict__ bsums, int n) {
  __shared__ int sm[2][512];
  int t = threadIdx.x;
  int gid = blockIdx.x * 512 + t;
  int v = (gid < n) ? in[gid] : 0;
  int pp = 0;
  sm[0][t] = v;
  __syncthreads();
  for (int off = 1; off < 512; off <<= 1) {
    int nv = sm[pp][t];
    if (t >= off) nv += sm[pp][t - off];
    sm[pp ^ 1][t] = nv;
    pp ^= 1;
    __syncthreads();
  }
  int inc = sm[pp][t];
  if (gid < n) tmp[gid] = inc;
  if (t == 511) bsums[blockIdx.x] = inc;
}

__global__ __launch_bounds__(256) void scan2_kernel(int* bsums, int nb) {
  __shared__ int sm[2][256];
  int t = threadIdx.x;
  int v = (t < nb) ? bsums[t] : 0;
  int pp = 0;
  sm[0][t] = v;
  __syncthreads();
  for (int off = 1; off < 256; off <<= 1) {
    int nv = sm[pp][t];
    if (t >= off) nv += sm[pp][t - off];
    sm[pp ^ 1][t] = nv;
    pp ^= 1;
    __syncthreads();
  }
  int inc = sm[pp][t];
  if (t < nb) bsums[t] = inc - v;  // exclusive
}

// rowptr from scan, plus dinv = rsqrt(deg+1) fused here
__global__ __launch_bounds__(256) void scan3_kernel(const int* __restrict__ tmp,
                                                    const int* __restrict__ bsums,
                                                    const int* __restrict__ deg,
                                                    int* __restrict__ rowptr,
                                                    float* __restrict__ dinv, int n) {
  int gid = blockIdx.x * 256 + threadIdx.x;
  if (gid < n) {
    rowptr[gid + 1] = tmp[gid] + bsums[gid >> 9];
    dinv[gid] = rsqrtf((float)(deg[gid] + 1));  // +1 self loop
  }
  if (gid == 0) rowptr[0] = 0;
}

// CSR scatter: one int2 {src, eid} store per edge; 4 edges/thread for MLP.
__global__ __launch_bounds__(256) void scatter_kernel(const int* __restrict__ src,
                                                      const int* __restrict__ dst,
                                                      const int* __restrict__ rowptr,
                                                      int* __restrict__ cnt,
                                                      int2* __restrict__ csr, int E) {
  int base = blockIdx.x * 1024 + threadIdx.x;
#pragma unroll
  for (int i = 0; i < 4; ++i) {
    int e = base + i * 256;
    if (e < E) {
      int d = dst[e];
      int pos = rowptr[d] + atomicAdd(&cnt[d], 1);
      csr[pos] = make_int2(src[e], e);
    }
  }
}

// ---------- pack W[128][128] fp32 -> bf16 hi/lo in MFMA B-fragment order ----
// B frag (16x16x32): lane holds B[k=(lane>>4)*8+j][n=lane&15], j=0..7.
// Layout: Wp[half(0=hi,1=lo)][ct(8)][kf(4)][lane(64)][8] bf16.
__global__ __launch_bounds__(256) void wpack_kernel(const float* __restrict__ W,
                                                    short* __restrict__ Wp) {
  int t = blockIdx.x * 256 + threadIdx.x;  // 2048 = ct*256 + kf*64 + lane
  if (t >= 2048) return;
  int lane = t & 63;
  int kf = (t >> 6) & 3;
  int ct = t >> 8;
  int col = ct * 16 + (lane & 15);
  int k0 = kf * 32 + (lane >> 4) * 8;
  short* dh = Wp + ((((0 * 8 + ct) * 4 + kf) * 64) + lane) * 8;
  short* dl = Wp + ((((1 * 8 + ct) * 4 + kf) * 64) + lane) * 8;
  for (int j = 0; j < 8; ++j) {
    float w = W[(k0 + j) * 128 + col];
    unsigned h = bf16_rne(w);
    float hf = __builtin_bit_cast(float, h << 16);
    unsigned lo = bf16_rne(w - hf);
    dh[j] = (short)h;
    dl[j] = (short)lo;
  }
}

// ---------- bf16 MFMA GEMM: out[r,:] = bf16( dinv[r] * (A[r,:] @ W) ) ----
// FP32A=true: A fp32 (layer 1, reads x); FP32A=false: A bf16 (layer 2).
// R16 structure: wave = one 16-col tile (ct = cg*4+wave); cg = blockIdx.x&1
// splits the 8 col-tiles across 2 blocks; rt = blockIdx.x>>1 is the 64-row
// tile. Straight-line 4 stages of 16 rows; stage t+1's A loads issue before
// stage t's MFMAs (depth-1 prefetch); hi/lo accumulated in SPLIT chains.
// Fast path (full tile) has zero per-access predicates.
template <bool FP32A>
__global__ __launch_bounds__(256, 4) void gemm_kernel(const void* __restrict__ Av,
                                                      const short* __restrict__ Wp,
                                                      const float* __restrict__ dinv,
                                                      unsigned short* __restrict__ out,
                                                      int M) {
  const int tid = threadIdx.x;
  const int wave = tid >> 6;
  const int lane = tid & 63;
  const int quad = lane >> 4;
  const int l15 = lane & 15;

  const int cg = blockIdx.x & 1;
  const int rt = blockIdx.x >> 1;
  const int ct = cg * 4 + wave;
  const int colbase = ct * 16 + l15;
  const int rb0 = rt * 64;

  // raw A staging (per stage): fp32 path 8 float4, bf16 path 4 short8
  float4 rawf[4][8];
  short8 rawb[4][4];
  const short8 s8z = {0, 0, 0, 0, 0, 0, 0, 0};

  auto issue = [&](int t) {
    const int arow = rb0 + t * 16 + l15;
    if constexpr (FP32A) {
      const float4* A4 = (const float4*)Av + (size_t)arow * 32;
#pragma unroll
      for (int u = 0; u < 8; ++u) rawf[t][u] = A4[(u >> 1) * 8 + quad * 2 + (u & 1)];
    } else {
      const unsigned short* A2 = (const unsigned short*)Av + (size_t)arow * 128;
#pragma unroll
      for (int f = 0; f < 4; ++f) rawb[t][f] = *(const short8*)(A2 + f * 32 + quad * 8);
    }
  };
  auto convert = [&](int t, short8 (&af)[4]) {
    if constexpr (FP32A) {
#pragma unroll
      for (int f = 0; f < 4; ++f) {
        const float4 a0 = rawf[t][f * 2];
        const float4 a1 = rawf[t][f * 2 + 1];
        const float av[8] = {a0.x, a0.y, a0.z, a0.w, a1.x, a1.y, a1.z, a1.w};
#pragma unroll
        for (int j = 0; j < 8; ++j) af[f][j] = (short)bf16_rne(av[j]);
      }
    } else {
#pragma unroll
      for (int f = 0; f < 4; ++f) af[f] = rawb[t][f];
    }
  };

  if (rb0 + 64 <= M) {
    // ---- fast path: no per-access predicates ----
    issue(0);  // start A stream before W loads

    // W fragments for this wave's col-tile: hi+lo x 4 kf = 32 VGPRs
    short8 Bh[4], Bl[4];
    const short8* Wp8 = (const short8*)Wp;
#pragma unroll
    for (int f = 0; f < 4; ++f) {
      Bh[f] = Wp8[((0 * 8 + ct) * 4 + f) * 64 + lane];
      Bl[f] = Wp8[((1 * 8 + ct) * 4 + f) * 64 + lane];
    }

#pragma unroll
    for (int t = 0; t < 4; ++t) {
      if (t < 3) issue(t + 1);  // prefetch next stage's A under this compute
      const f32x4 dv = *(const f32x4*)(dinv + rb0 + t * 16 + quad * 4);
      short8 af[4];
      convert(t, af);
      f32x4 ah = {0.f, 0.f, 0.f, 0.f};
      f32x4 al = {0.f, 0.f, 0.f, 0.f};
#pragma unroll
      for (int f = 0; f < 4; ++f) {
        ah = __builtin_amdgcn_mfma_f32_16x16x32_bf16(af[f], Bh[f], ah, 0, 0, 0);
        al = __builtin_amdgcn_mfma_f32_16x16x32_bf16(af[f], Bl[f], al, 0, 0, 0);
      }
#pragma unroll
      for (int i = 0; i < 4; ++i) {
        const int r = rb0 + t * 16 + quad * 4 + i;
        out[(size_t)r * 128 + colbase] =
            (unsigned short)bf16_rne((ah[i] + al[i]) * dv[i]);
      }
    }
  } else {
    // ---- tail path: ~2 blocks, fully guarded ----
    short8 Bh[4], Bl[4];
    const short8* Wp8 = (const short8*)Wp;
#pragma unroll
    for (int f = 0; f < 4; ++f) {
      Bh[f] = Wp8[((0 * 8 + ct) * 4 + f) * 64 + lane];
      Bl[f] = Wp8[((1 * 8 + ct) * 4 + f) * 64 + lane];
    }
#pragma unroll 1
    for (int t = 0; t < 4; ++t) {
      const int rb = rb0 + t * 16;
      if (rb >= M) break;
      const int arow = rb + l15;
      const bool rok = arow < M;
      short8 af[4];
      if constexpr (FP32A) {
        const float4* A4 = (const float4*)Av + (size_t)arow * 32;
#pragma unroll
        for (int f = 0; f < 4; ++f) {
          if (rok) {
            float4 a0 = A4[f * 8 + quad * 2];
            float4 a1 = A4[f * 8 + quad * 2 + 1];
            float av[8] = {a0.x, a0.y, a0.z, a0.w, a1.x, a1.y, a1.z, a1.w};
#pragma unroll
            for (int j = 0; j < 8; ++j) af[f][j] = (short)bf16_rne(av[j]);
          } else {
            af[f] = s8z;
          }
        }
      } else {
        const unsigned short* A2 = (const unsigned short*)Av + (size_t)arow * 128;
#pragma unroll
        for (int f = 0; f < 4; ++f)
          af[f] = rok ? *(const short8*)(A2 + f * 32 + quad * 8) : s8z;
      }
      f32x4 ah = {0.f, 0.f, 0.f, 0.f};
      f32x4 al = {0.f, 0.f, 0.f, 0.f};
#pragma unroll
      for (int f = 0; f < 4; ++f) {
        ah = __builtin_amdgcn_mfma_f32_16x16x32_bf16(af[f], Bh[f], ah, 0, 0, 0);
        al = __builtin_amdgcn_mfma_f32_16x16x32_bf16(af[f], Bl[f], al, 0, 0, 0);
      }
#pragma unroll
      for (int i = 0; i < 4; ++i) {
        const int r = rb + quad * 4 + i;
        if (r < M) {
          out[(size_t)r * 128 + colbase] =
              (unsigned short)bf16_rne((ah[i] + al[i]) * dinv[r]);
        }
      }
    }
  }
}

// ---------- aggregation over prescaled bf16 rows ----------
// out[i] = bf16( dinv[i]*(xw[i] + sum_j xw[j]) + b ), fp32 accumulation.
// 16 lanes/node, one ushort8 (16B) per lane per row, neighbor unroll x4.
__global__ __launch_bounds__(256) void agg_kernel(const unsigned short* __restrict__ xw,
                                                  const float* __restrict__ dinv,
                                                  const int* __restrict__ rowptr,
                                                  const int2* __restrict__ csr,
                                                  const float* __restrict__ bias,
                                                  unsigned short* __restrict__ out,
                                                  int relu, int N) {
  int node = blockIdx.x * 16 + (threadIdx.x >> 4);
  int l = threadIdx.x & 15;
  if (node >= N) return;
  const short8* xw8 = (const short8*)xw;  // row = 16 short8 groups
  short8 sv = xw8[(size_t)node * 16 + l];
  float acc[8];
#pragma unroll
  for (int j = 0; j < 8; ++j) acc[j] = bf2f((unsigned short)sv[j]);
  int s = rowptr[node], e = rowptr[node + 1];
  int k = s;
  for (; k + 4 <= e; k += 4) {
    int j0 = csr[k].x, j1 = csr[k + 1].x, j2 = csr[k + 2].x, j3 = csr[k + 3].x;
    short8 v0 = xw8[(size_t)j0 * 16 + l];
    short8 v1 = xw8[(size_t)j1 * 16 + l];
    short8 v2 = xw8[(size_t)j2 * 16 + l];
    short8 v3 = xw8[(size_t)j3 * 16 + l];
#pragma unroll
    for (int j = 0; j < 8; ++j) {
      acc[j] += (bf2f((unsigned short)v0[j]) + bf2f((unsigned short)v1[j])) +
                (bf2f((unsigned short)v2[j]) + bf2f((unsigned short)v3[j]));
    }
  }
  for (; k < e; ++k) {
    short8 v = xw8[(size_t)csr[k].x * 16 + l];
#pragma unroll
    for (int j = 0; j < 8; ++j) acc[j] += bf2f((unsigned short)v[j]);
  }
  float di = dinv[node];
  const float4* b4 = (const float4*)bias;
  float4 bb0 = b4[l * 2], bb1 = b4[l * 2 + 1];
  float bv[8] = {bb0.x, bb0.y, bb0.z, bb0.w, bb1.x, bb1.y, bb1.z, bb1.w};
  short8 o;
#pragma unroll
  for (int j = 0; j < 8; ++j) {
    float v = fmaf(di, acc[j], bv[j]);
    if (relu) v = fmaxf(v, 0.f);
    o[j] = (short)bf16_rne(v);
  }
  ((short8*)out)[(size_t)node * 16 + l] = o;
}

// ---------- decode over dst-CSR, bf16 z2: 16 lanes/node ----------
__global__ __launch_bounds__(256) void decode_kernel(const unsigned short* __restrict__ z,
                                                     const int* __restrict__ rowptr,
                                                     const int2* __restrict__ csr,
                                                     float* __restrict__ out, int N) {
  int node = blockIdx.x * 16 + (threadIdx.x >> 4);
  int l = threadIdx.x & 15;
  if (node >= N) return;
  const short8* z8 = (const short8*)z;
  short8 zv = z8[(size_t)node * 16 + l];
  float zd[8];
#pragma unroll
  for (int j = 0; j < 8; ++j) zd[j] = bf2f((unsigned short)zv[j]);
  int s = rowptr[node], e = rowptr[node + 1];
  int k = s;
  for (; k + 4 <= e; k += 4) {
    int2 c0 = csr[k], c1 = csr[k + 1], c2 = csr[k + 2], c3 = csr[k + 3];
    short8 v0 = z8[(size_t)c0.x * 16 + l];
    short8 v1 = z8[(size_t)c1.x * 16 + l];
    short8 v2 = z8[(size_t)c2.x * 16 + l];
    short8 v3 = z8[(size_t)c3.x * 16 + l];
    float p0 = 0.f, p1 = 0.f, p2 = 0.f, p3 = 0.f;
#pragma unroll
    for (int j = 0; j < 8; ++j) {
      p0 = fmaf(zd[j], bf2f((unsigned short)v0[j]), p0);
      p1 = fmaf(zd[j], bf2f((unsigned short)v1[j]), p1);
      p2 = fmaf(zd[j], bf2f((unsigned short)v2[j]), p2);
      p3 = fmaf(zd[j], bf2f((unsigned short)v3[j]), p3);
    }
#pragma unroll
    for (int off = 8; off > 0; off >>= 1) {
      p0 += __shfl_xor(p0, off);
      p1 += __shfl_xor(p1, off);
      p2 += __shfl_xor(p2, off);
      p3 += __shfl_xor(p3, off);
    }
    if (l == 0) {
      out[c0.y] = p0;
      out[c1.y] = p1;
      out[c2.y] = p2;
      out[c3.y] = p3;
    }
  }
  for (; k < e; ++k) {
    int2 c = csr[k];
    short8 v = z8[(size_t)c.x * 16 + l];
    float p = 0.f;
#pragma unroll
    for (int j = 0; j < 8; ++j) p = fmaf(zd[j], bf2f((unsigned short)v[j]), p);
#pragma unroll
    for (int off = 8; off > 0; off >>= 1) p += __shfl_xor(p, off);
    if (l == 0) out[c.y] = p;
  }
}

extern "C" void kernel_launch(void* const* d_in, const int* in_sizes, int n_in,
                              void* d_out, int out_size, void* d_ws, size_t ws_size,
                              hipStream_t stream) {
  const float* x  = (const float*)d_in[0];
  const int*   ei = (const int*)d_in[1];
  const float* W1 = (const float*)d_in[2];
  const float* b1 = (const float*)d_in[3];
  const float* W2 = (const float*)d_in[4];
  const float* b2 = (const float*)d_in[5];

  const int N = in_sizes[0] / 128;
  const int E = in_sizes[1] / 2;
  const int* src = ei;
  const int* dst = ei + E;

  char* ws = (char*)d_ws;
  size_t off = 0;
  auto alloc = [&](size_t bytes) -> void* {
    void* p = ws + off;
    off += (bytes + 255) & ~(size_t)255;
    return p;
  };
  unsigned short* bufA = (unsigned short*)alloc((size_t)N * 128 * 2);
  unsigned short* bufB = (unsigned short*)alloc((size_t)N * 128 * 2);
  float* dinv    = (float*)alloc((size_t)N * 4);
  int*   rowptr  = (int*)alloc((size_t)(N + 1) * 4);
  int2*  csr     = (int2*)alloc((size_t)E * 8);
  short* Wp1     = (short*)alloc((size_t)2 * 8 * 4 * 64 * 8 * 2);
  short* Wp2     = (short*)alloc((size_t)2 * 8 * 4 * 64 * 8 * 2);
  int*   tmp     = (int*)alloc((size_t)N * 4);
  int*   deg     = (int*)alloc((size_t)N * 4);   // zeroed region starts here
  int*   cnt     = (int*)alloc((size_t)N * 4);
  int*   bsums   = (int*)alloc(1024);
  size_t zbytes = ((char*)bsums + 1024) - (char*)deg;
  hipMemsetAsync(deg, 0, zbytes, stream);

  const int E4B = (E + 1023) / 1024;
  const int NB = (N + 255) / 256;
  const int SB = (N + 511) / 512;

  // W packing (independent of graph prep)
  wpack_kernel<<<8, 256, 0, stream>>>(W1, Wp1);
  wpack_kernel<<<8, 256, 0, stream>>>(W2, Wp2);

  deg_kernel<<<E4B, 256, 0, stream>>>(dst, deg, E);
  scan1_kernel<<<SB, 512, 0, stream>>>(deg, tmp, bsums, N);
  scan2_kernel<<<1, 256, 0, stream>>>(bsums, SB);
  scan3_kernel<<<NB, 256, 0, stream>>>(tmp, bsums, deg, rowptr, dinv, N);
  scatter_kernel<<<E4B, 256, 0, stream>>>(src, dst, rowptr, cnt, csr, E);

  const int GB = 2 * ((N + 63) / 64);
  const int AB = (N + 15) / 16;
  const int DB = (N + 15) / 16;

  // layer 1 (A = x, fp32 -> bf16 in-register)
  gemm_kernel<true><<<GB, 256, 0, stream>>>(x, Wp1, dinv, bufA, N);
  agg_kernel<<<AB, 256, 0, stream>>>(bufA, dinv, rowptr, csr, b1, bufB, 1, N);
  // layer 2 (A = z1, bf16)
  gemm_kernel<false><<<GB, 256, 0, stream>>>(bufB, Wp2, dinv, bufA, N);
  agg_kernel<<<AB, 256, 0, stream>>>(bufA, dinv, rowptr, csr, b2, bufB, 0, N);
  // decode over dst-CSR
  decode_kernel<<<DB, 256, 0, stream>>>(bufB, rowptr, csr, (float*)d_out, N);
}

// Round 7
// 333.302 us; speedup vs baseline: 1.0850x; 1.0171x over previous
//
#include <hip/hip_runtime.h>

// GCN link predictor: z1 = relu(GCNConv(x,W1,b1)); z2 = GCNConv(z1,W2,b2);
// out[e] = dot(z2[src[e]], z2[dst[e]])
// R9: full bf16 data plane, bf16 MFMA GEMM (hi/lo split for accuracy).
// R10: 50us gemm BEST. 64-row blocks, wave=2 ct, W re-fetched from L2/stage.
// R11 FAILED: reg-resident W -> spill, 130us.
// R12/R13 FAILED: 64KB LDS-W big blocks -> occ 11%, 79us.
// R14 FAILED: 1ct/wave + cg split -> 69us (A traffic 2x, fewer MFMA/stage).
// R15 FAILED: LDS-W 512t -> 75us. W-from-L2 is FINE; W-residency is a dead end
//      (compiler sinks const __restrict__ global loads, 4 attempts).
// R16: straight-line + A-prefetch + split acc chains on R14 skeleton: 69->60.
// R17: transplant R16 micro-opts onto R10 geometry (the empirical best):
//      grid ceil(M/64) (A read ONCE), 4 waves x 2 col-tiles = 16 MFMA/stage,
//      straight-line 4 stages, depth-1 A prefetch, FOUR independent acc
//      chains (a0h/a1h/a0l/a1l), f32x4 dinv load, zero-predicate fast path.
//      launch_bounds(256,4): cap 128 so prefetch dbuf fits, B sinks (ok).

typedef __attribute__((ext_vector_type(8))) short short8;  // 8 bf16 = 4 VGPRs
typedef __attribute__((ext_vector_type(4))) float f32x4;

__device__ __forceinline__ unsigned bf16_rne(float x) {
  unsigned u = __builtin_bit_cast(unsigned, x);
  return (u + 0x7FFFu + ((u >> 16) & 1u)) >> 16;
}
__device__ __forceinline__ float bf2f(unsigned short u) {
  return __builtin_bit_cast(float, ((unsigned)u) << 16);
}

// ---------- degree: 4 edges/thread ----------
__global__ __launch_bounds__(256) void deg_kernel(const int* __restrict__ dst,
                                                  int* __restrict__ deg, int E) {
  int base = blockIdx.x * 1024 + threadIdx.x;
#pragma unroll
  for (int i = 0; i < 4; ++i) {
    int e = base + i * 256;
    if (e < E) atomicAdd(&deg[dst[e]], 1);
  }
}

// ---------- block scan (512 elems/block) ----------
__global__ __launch_bounds__(512) void scan1_kernel(const int* __restrict__ in,
                                                    int* __restrict__ tmp,
                                                    int* __restrict__ bsums, int n) {
  __shared__ int sm[2][512];
  int t = threadIdx.x;
  int gid = blockIdx.x * 512 + t;
  int v = (gid < n) ? in[gid] : 0;
  int pp = 0;
  sm[0][t] = v;
  __syncthreads();
  for (int off = 1; off < 512; off <<= 1) {
    int nv = sm[pp][t];
    if (t >= off) nv += sm[pp][t - off];
    sm[pp ^ 1][t] = nv;
    pp ^= 1;
    __syncthreads();
  }
  int inc = sm[pp][t];
  if (gid < n) tmp[gid] = inc;
  if (t == 511) bsums[blockIdx.x] = inc;
}

__global__ __launch_bounds__(256) void scan2_kernel(int* bsums, int nb) {
  __shared__ int sm[2][256];
  int t = threadIdx.x;
  int v = (t < nb) ? bsums[t] : 0;
  int pp = 0;
  sm[0][t] = v;
  __syncthreads();
  for (int off = 1; off < 256; off <<= 1) {
    int nv = sm[pp][t];
    if (t >= off) nv += sm[pp][t - off];
    sm[pp ^ 1][t] = nv;
    pp ^= 1;
    __syncthreads();
  }
  int inc = sm[pp][t];
  if (t < nb) bsums[t] = inc - v;  // exclusive
}

// rowptr from scan, plus dinv = rsqrt(deg+1) fused here
__global__ __launch_bounds__(256) void scan3_kernel(const int* __restrict__ tmp,
                                                    const int* __restrict__ bsums,
                                                    const int* __restrict__ deg,
                                                    int* __restrict__ rowptr,
                                                    float* __restrict__ dinv, int n) {
  int gid = blockIdx.x * 256 + threadIdx.x;
  if (gid < n) {
    rowptr[gid + 1] = tmp[gid] + bsums[gid >> 9];
    dinv[gid] = rsqrtf((float)(deg[gid] + 1));  // +1 self loop
  }
  if (gid == 0) rowptr[0] = 0;
}

// CSR scatter: one int2 {src, eid} store per edge; 4 edges/thread for MLP.
__global__ __launch_bounds__(256) void scatter_kernel(const int* __restrict__ src,
                                                      const int* __restrict__ dst,
                                                      const int* __restrict__ rowptr,
                                                      int* __restrict__ cnt,
                                                      int2* __restrict__ csr, int E) {
  int base = blockIdx.x * 1024 + threadIdx.x;
#pragma unroll
  for (int i = 0; i < 4; ++i) {
    int e = base + i * 256;
    if (e < E) {
      int d = dst[e];
      int pos = rowptr[d] + atomicAdd(&cnt[d], 1);
      csr[pos] = make_int2(src[e], e);
    }
  }
}

// ---------- pack W[128][128] fp32 -> bf16 hi/lo in MFMA B-fragment order ----
// B frag (16x16x32): lane holds B[k=(lane>>4)*8+j][n=lane&15], j=0..7.
// Layout: Wp[half(0=hi,1=lo)][ct(8)][kf(4)][lane(64)][8] bf16.
__global__ __launch_bounds__(256) void wpack_kernel(const float* __restrict__ W,
                                                    short* __restrict__ Wp) {
  int t = blockIdx.x * 256 + threadIdx.x;  // 2048 = ct*256 + kf*64 + lane
  if (t >= 2048) return;
  int lane = t & 63;
  int kf = (t >> 6) & 3;
  int ct = t >> 8;
  int col = ct * 16 + (lane & 15);
  int k0 = kf * 32 + (lane >> 4) * 8;
  short* dh = Wp + ((((0 * 8 + ct) * 4 + kf) * 64) + lane) * 8;
  short* dl = Wp + ((((1 * 8 + ct) * 4 + kf) * 64) + lane) * 8;
  for (int j = 0; j < 8; ++j) {
    float w = W[(k0 + j) * 128 + col];
    unsigned h = bf16_rne(w);
    float hf = __builtin_bit_cast(float, h << 16);
    unsigned lo = bf16_rne(w - hf);
    dh[j] = (short)h;
    dl[j] = (short)lo;
  }
}

// ---------- bf16 MFMA GEMM: out[r,:] = bf16( dinv[r] * (A[r,:] @ W) ) ----
// FP32A=true: A fp32 (layer 1, reads x); FP32A=false: A bf16 (layer 2).
// R17 structure: block = 64 rows x 128 cols, 4 waves, wave = 2 col-tiles
// (ct0=2*wave, ct1=2*wave+1) -> 16 MFMAs/stage/wave. Straight-line 4 stages;
// stage t+1's A loads issue before stage t's MFMAs (depth-1 prefetch);
// hi/lo x 2ct accumulate in FOUR independent chains. Fast path (full tile)
// has zero per-access predicates. W fragments come from L2 per stage (the
// compiler sinks them; measured-fast in R10).
template <bool FP32A>
__global__ __launch_bounds__(256, 4) void gemm_kernel(const void* __restrict__ Av,
                                                      const short* __restrict__ Wp,
                                                      const float* __restrict__ dinv,
                                                      unsigned short* __restrict__ out,
                                                      int M) {
  const int tid = threadIdx.x;
  const int wave = tid >> 6;
  const int lane = tid & 63;
  const int quad = lane >> 4;
  const int l15 = lane & 15;

  const int ct0 = wave * 2;
  const int ct1 = wave * 2 + 1;
  const int colbase = wave * 32 + l15;
  const int rb0 = blockIdx.x * 64;

  // raw A staging (per stage): fp32 path 8 float4, bf16 path 4 short8
  float4 rawf[4][8];
  short8 rawb[4][4];
  const short8 s8z = {0, 0, 0, 0, 0, 0, 0, 0};
  const short8* Wp8 = (const short8*)Wp;

  auto issue = [&](int t) {
    const int arow = rb0 + t * 16 + l15;
    if constexpr (FP32A) {
      const float4* A4 = (const float4*)Av + (size_t)arow * 32;
#pragma unroll
      for (int u = 0; u < 8; ++u) rawf[t][u] = A4[(u >> 1) * 8 + quad * 2 + (u & 1)];
    } else {
      const unsigned short* A2 = (const unsigned short*)Av + (size_t)arow * 128;
#pragma unroll
      for (int f = 0; f < 4; ++f) rawb[t][f] = *(const short8*)(A2 + f * 32 + quad * 8);
    }
  };
  auto convert = [&](int t, short8 (&af)[4]) {
    if constexpr (FP32A) {
#pragma unroll
      for (int f = 0; f < 4; ++f) {
        const float4 a0 = rawf[t][f * 2];
        const float4 a1 = rawf[t][f * 2 + 1];
        const float av[8] = {a0.x, a0.y, a0.z, a0.w, a1.x, a1.y, a1.z, a1.w};
#pragma unroll
        for (int j = 0; j < 8; ++j) af[f][j] = (short)bf16_rne(av[j]);
      }
    } else {
#pragma unroll
      for (int f = 0; f < 4; ++f) af[f] = rawb[t][f];
    }
  };

  if (rb0 + 64 <= M) {
    // ---- fast path: no per-access predicates ----
    issue(0);  // A stream starts first

#pragma unroll
    for (int t = 0; t < 4; ++t) {
      if (t < 3) issue(t + 1);  // prefetch next stage's A under this compute
      const f32x4 dv = *(const f32x4*)(dinv + rb0 + t * 16 + quad * 4);
      short8 af[4];
      convert(t, af);
      f32x4 a0h = {0.f, 0.f, 0.f, 0.f};
      f32x4 a0l = {0.f, 0.f, 0.f, 0.f};
      f32x4 a1h = {0.f, 0.f, 0.f, 0.f};
      f32x4 a1l = {0.f, 0.f, 0.f, 0.f};
#pragma unroll
      for (int f = 0; f < 4; ++f) {
        const short8 bh0 = Wp8[((0 * 8 + ct0) * 4 + f) * 64 + lane];
        const short8 bh1 = Wp8[((0 * 8 + ct1) * 4 + f) * 64 + lane];
        const short8 bl0 = Wp8[((1 * 8 + ct0) * 4 + f) * 64 + lane];
        const short8 bl1 = Wp8[((1 * 8 + ct1) * 4 + f) * 64 + lane];
        a0h = __builtin_amdgcn_mfma_f32_16x16x32_bf16(af[f], bh0, a0h, 0, 0, 0);
        a1h = __builtin_amdgcn_mfma_f32_16x16x32_bf16(af[f], bh1, a1h, 0, 0, 0);
        a0l = __builtin_amdgcn_mfma_f32_16x16x32_bf16(af[f], bl0, a0l, 0, 0, 0);
        a1l = __builtin_amdgcn_mfma_f32_16x16x32_bf16(af[f], bl1, a1l, 0, 0, 0);
      }
#pragma unroll
      for (int i = 0; i < 4; ++i) {
        const int r = rb0 + t * 16 + quad * 4 + i;
        out[(size_t)r * 128 + colbase] =
            (unsigned short)bf16_rne((a0h[i] + a0l[i]) * dv[i]);
        out[(size_t)r * 128 + colbase + 16] =
            (unsigned short)bf16_rne((a1h[i] + a1l[i]) * dv[i]);
      }
    }
  } else {
    // ---- tail path: ~1 block, fully guarded ----
#pragma unroll 1
    for (int t = 0; t < 4; ++t) {
      const int rb = rb0 + t * 16;
      if (rb >= M) break;
      const int arow = rb + l15;
      const bool rok = arow < M;
      short8 af[4];
      if constexpr (FP32A) {
        const float4* A4 = (const float4*)Av + (size_t)arow * 32;
#pragma unroll
        for (int f = 0; f < 4; ++f) {
          if (rok) {
            float4 a0 = A4[f * 8 + quad * 2];
            float4 a1 = A4[f * 8 + quad * 2 + 1];
            float av[8] = {a0.x, a0.y, a0.z, a0.w, a1.x, a1.y, a1.z, a1.w};
#pragma unroll
            for (int j = 0; j < 8; ++j) af[f][j] = (short)bf16_rne(av[j]);
          } else {
            af[f] = s8z;
          }
        }
      } else {
        const unsigned short* A2 = (const unsigned short*)Av + (size_t)arow * 128;
#pragma unroll
        for (int f = 0; f < 4; ++f)
          af[f] = rok ? *(const short8*)(A2 + f * 32 + quad * 8) : s8z;
      }
      f32x4 a0h = {0.f, 0.f, 0.f, 0.f};
      f32x4 a0l = {0.f, 0.f, 0.f, 0.f};
      f32x4 a1h = {0.f, 0.f, 0.f, 0.f};
      f32x4 a1l = {0.f, 0.f, 0.f, 0.f};
#pragma unroll
      for (int f = 0; f < 4; ++f) {
        const short8 bh0 = Wp8[((0 * 8 + ct0) * 4 + f) * 64 + lane];
        const short8 bh1 = Wp8[((0 * 8 + ct1) * 4 + f) * 64 + lane];
        const short8 bl0 = Wp8[((1 * 8 + ct0) * 4 + f) * 64 + lane];
        const short8 bl1 = Wp8[((1 * 8 + ct1) * 4 + f) * 64 + lane];
        a0h = __builtin_amdgcn_mfma_f32_16x16x32_bf16(af[f], bh0, a0h, 0, 0, 0);
        a1h = __builtin_amdgcn_mfma_f32_16x16x32_bf16(af[f], bh1, a1h, 0, 0, 0);
        a0l = __builtin_amdgcn_mfma_f32_16x16x32_bf16(af[f], bl0, a0l, 0, 0, 0);
        a1l = __builtin_amdgcn_mfma_f32_16x16x32_bf16(af[f], bl1, a1l, 0, 0, 0);
      }
#pragma unroll
      for (int i = 0; i < 4; ++i) {
        const int r = rb + quad * 4 + i;
        if (r < M) {
          const float d = dinv[r];
          out[(size_t)r * 128 + colbase] =
              (unsigned short)bf16_rne((a0h[i] + a0l[i]) * d);
          out[(size_t)r * 128 + colbase + 16] =
              (unsigned short)bf16_rne((a1h[i] + a1l[i]) * d);
        }
      }
    }
  }
}

// ---------- aggregation over prescaled bf16 rows ----------
// out[i] = bf16( dinv[i]*(xw[i] + sum_j xw[j]) + b ), fp32 accumulation.
// 16 lanes/node, one ushort8 (16B) per lane per row, neighbor unroll x4.
__global__ __launch_bounds__(256) void agg_kernel(const unsigned short* __restrict__ xw,
                                                  const float* __restrict__ dinv,
                                                  const int* __restrict__ rowptr,
                                                  const int2* __restrict__ csr,
                                                  const float* __restrict__ bias,
                                                  unsigned short* __restrict__ out,
                                                  int relu, int N) {
  int node = blockIdx.x * 16 + (threadIdx.x >> 4);
  int l = threadIdx.x & 15;
  if (node >= N) return;
  const short8* xw8 = (const short8*)xw;  // row = 16 short8 groups
  short8 sv = xw8[(size_t)node * 16 + l];
  float acc[8];
#pragma unroll
  for (int j = 0; j < 8; ++j) acc[j] = bf2f((unsigned short)sv[j]);
  int s = rowptr[node], e = rowptr[node + 1];
  int k = s;
  for (; k + 4 <= e; k += 4) {
    int j0 = csr[k].x, j1 = csr[k + 1].x, j2 = csr[k + 2].x, j3 = csr[k + 3].x;
    short8 v0 = xw8[(size_t)j0 * 16 + l];
    short8 v1 = xw8[(size_t)j1 * 16 + l];
    short8 v2 = xw8[(size_t)j2 * 16 + l];
    short8 v3 = xw8[(size_t)j3 * 16 + l];
#pragma unroll
    for (int j = 0; j < 8; ++j) {
      acc[j] += (bf2f((unsigned short)v0[j]) + bf2f((unsigned short)v1[j])) +
                (bf2f((unsigned short)v2[j]) + bf2f((unsigned short)v3[j]));
    }
  }
  for (; k < e; ++k) {
    short8 v = xw8[(size_t)csr[k].x * 16 + l];
#pragma unroll
    for (int j = 0; j < 8; ++j) acc[j] += bf2f((unsigned short)v[j]);
  }
  float di = dinv[node];
  const float4* b4 = (const float4*)bias;
  float4 bb0 = b4[l * 2], bb1 = b4[l * 2 + 1];
  float bv[8] = {bb0.x, bb0.y, bb0.z, bb0.w, bb1.x, bb1.y, bb1.z, bb1.w};
  short8 o;
#pragma unroll
  for (int j = 0; j < 8; ++j) {
    float v = fmaf(di, acc[j], bv[j]);
    if (relu) v = fmaxf(v, 0.f);
    o[j] = (short)bf16_rne(v);
  }
  ((short8*)out)[(size_t)node * 16 + l] = o;
}

// ---------- decode over dst-CSR, bf16 z2: 16 lanes/node ----------
__global__ __launch_bounds__(256) void decode_kernel(const unsigned short* __restrict__ z,
                                                     const int* __restrict__ rowptr,
                                                     const int2* __restrict__ csr,
                                                     float* __restrict__ out, int N) {
  int node = blockIdx.x * 16 + (threadIdx.x >> 4);
  int l = threadIdx.x & 15;
  if (node >= N) return;
  const short8* z8 = (const short8*)z;
  short8 zv = z8[(size_t)node * 16 + l];
  float zd[8];
#pragma unroll
  for (int j = 0; j < 8; ++j) zd[j] = bf2f((unsigned short)zv[j]);
  int s = rowptr[node], e = rowptr[node + 1];
  int k = s;
  for (; k + 4 <= e; k += 4) {
    int2 c0 = csr[k], c1 = csr[k + 1], c2 = csr[k + 2], c3 = csr[k + 3];
    short8 v0 = z8[(size_t)c0.x * 16 + l];
    short8 v1 = z8[(size_t)c1.x * 16 + l];
    short8 v2 = z8[(size_t)c2.x * 16 + l];
    short8 v3 = z8[(size_t)c3.x * 16 + l];
    float p0 = 0.f, p1 = 0.f, p2 = 0.f, p3 = 0.f;
#pragma unroll
    for (int j = 0; j < 8; ++j) {
      p0 = fmaf(zd[j], bf2f((unsigned short)v0[j]), p0);
      p1 = fmaf(zd[j], bf2f((unsigned short)v1[j]), p1);
      p2 = fmaf(zd[j], bf2f((unsigned short)v2[j]), p2);
      p3 = fmaf(zd[j], bf2f((unsigned short)v3[j]), p3);
    }
#pragma unroll
    for (int off = 8; off > 0; off >>= 1) {
      p0 += __shfl_xor(p0, off);
      p1 += __shfl_xor(p1, off);
      p2 += __shfl_xor(p2, off);
      p3 += __shfl_xor(p3, off);
    }
    if (l == 0) {
      out[c0.y] = p0;
      out[c1.y] = p1;
      out[c2.y] = p2;
      out[c3.y] = p3;
    }
  }
  for (; k < e; ++k) {
    int2 c = csr[k];
    short8 v = z8[(size_t)c.x * 16 + l];
    float p = 0.f;
#pragma unroll
    for (int j = 0; j < 8; ++j) p = fmaf(zd[j], bf2f((unsigned short)v[j]), p);
#pragma unroll
    for (int off = 8; off > 0; off >>= 1) p += __shfl_xor(p, off);
    if (l == 0) out[c.y] = p;
  }
}

extern "C" void kernel_launch(void* const* d_in, const int* in_sizes, int n_in,
                              void* d_out, int out_size, void* d_ws, size_t ws_size,
                              hipStream_t stream) {
  const float* x  = (const float*)d_in[0];
  const int*   ei = (const int*)d_in[1];
  const float* W1 = (const float*)d_in[2];
  const float* b1 = (const float*)d_in[3];
  const float* W2 = (const float*)d_in[4];
  const float* b2 = (const float*)d_in[5];

  const int N = in_sizes[0] / 128;
  const int E = in_sizes[1] / 2;
  const int* src = ei;
  const int* dst = ei + E;

  char* ws = (char*)d_ws;
  size_t off = 0;
  auto alloc = [&](size_t bytes) -> void* {
    void* p = ws + off;
    off += (bytes + 255) & ~(size_t)255;
    return p;
  };
  unsigned short* bufA = (unsigned short*)alloc((size_t)N * 128 * 2);
  unsigned short* bufB = (unsigned short*)alloc((size_t)N * 128 * 2);
  float* dinv    = (float*)alloc((size_t)N * 4);
  int*   rowptr  = (int*)alloc((size_t)(N + 1) * 4);
  int2*  csr     = (int2*)alloc((size_t)E * 8);
  short* Wp1     = (short*)alloc((size_t)2 * 8 * 4 * 64 * 8 * 2);
  short* Wp2     = (short*)alloc((size_t)2 * 8 * 4 * 64 * 8 * 2);
  int*   tmp     = (int*)alloc((size_t)N * 4);
  int*   deg     = (int*)alloc((size_t)N * 4);   // zeroed region starts here
  int*   cnt     = (int*)alloc((size_t)N * 4);
  int*   bsums   = (int*)alloc(1024);
  size_t zbytes = ((char*)bsums + 1024) - (char*)deg;
  hipMemsetAsync(deg, 0, zbytes, stream);

  const int E4B = (E + 1023) / 1024;
  const int NB = (N + 255) / 256;
  const int SB = (N + 511) / 512;

  // W packing (independent of graph prep)
  wpack_kernel<<<8, 256, 0, stream>>>(W1, Wp1);
  wpack_kernel<<<8, 256, 0, stream>>>(W2, Wp2);

  deg_kernel<<<E4B, 256, 0, stream>>>(dst, deg, E);
  scan1_kernel<<<SB, 512, 0, stream>>>(deg, tmp, bsums, N);
  scan2_kernel<<<1, 256, 0, stream>>>(bsums, SB);
  scan3_kernel<<<NB, 256, 0, stream>>>(tmp, bsums, deg, rowptr, dinv, N);
  scatter_kernel<<<E4B, 256, 0, stream>>>(src, dst, rowptr, cnt, csr, E);

  const int GB = (N + 63) / 64;
  const int AB = (N + 15) / 16;
  const int DB = (N + 15) / 16;

  // layer 1 (A = x, fp32 -> bf16 in-register)
  gemm_kernel<true><<<GB, 256, 0, stream>>>(x, Wp1, dinv, bufA, N);
  agg_kernel<<<AB, 256, 0, stream>>>(bufA, dinv, rowptr, csr, b1, bufB, 1, N);
  // layer 2 (A = z1, bf16)
  gemm_kernel<false><<<GB, 256, 0, stream>>>(bufB, Wp2, dinv, bufA, N);
  agg_kernel<<<AB, 256, 0, stream>>>(bufA, dinv, rowptr, csr, b2, bufB, 0, N);
  // decode over dst-CSR
  decode_kernel<<<DB, 256, 0, stream>>>(bufB, rowptr, csr, (float*)d_out, N);
}

// Round 8
// 313.543 us; speedup vs baseline: 1.1534x; 1.0630x over previous
//
#include <hip/hip_runtime.h>

// GCN link predictor: z1 = relu(GCNConv(x,W1,b1)); z2 = GCNConv(z1,W2,b2);
// out[e] = dot(z2[src[e]], z2[dst[e]])
// R9-R17 history (gemm restructuring, 7 rounds): best standalone gemm ~50-60us,
//   latency-bound floor. Compiler refuses register residency for W and for
//   prefetch buffers (VGPR 44-52 every time) — 5 failed attempts. LDS-W and
//   occupancy tweaks shuffle 50-79us. STOP tuning the dispatch.
// R18: REMOVE a dispatch. Fuse gemm2 into agg1: an agg block's 16 nodes are
//   exactly one MFMA M=16 tile. agg computes relu'd z1 rows -> 4KB LDS tile
//   (XOR-swizzled chunks) -> barrier -> 4 waves do 16x128 @ 128x128 bf16
//   MFMA (wave = 2 col-tiles, hi/lo) -> write dinv*(z1@W2) directly.
//   Deletes: gemm2 dispatch (~57us latency), z1 write+read (51MB round trip).

typedef __attribute__((ext_vector_type(8))) short short8;  // 8 bf16 = 4 VGPRs
typedef __attribute__((ext_vector_type(4))) float f32x4;

__device__ __forceinline__ unsigned bf16_rne(float x) {
  unsigned u = __builtin_bit_cast(unsigned, x);
  return (u + 0x7FFFu + ((u >> 16) & 1u)) >> 16;
}
__device__ __forceinline__ float bf2f(unsigned short u) {
  return __builtin_bit_cast(float, ((unsigned)u) << 16);
}

// ---------- degree: 4 edges/thread ----------
__global__ __launch_bounds__(256) void deg_kernel(const int* __restrict__ dst,
                                                  int* __restrict__ deg, int E) {
  int base = blockIdx.x * 1024 + threadIdx.x;
#pragma unroll
  for (int i = 0; i < 4; ++i) {
    int e = base + i * 256;
    if (e < E) atomicAdd(&deg[dst[e]], 1);
  }
}

// ---------- block scan (512 elems/block) ----------
__global__ __launch_bounds__(512) void scan1_kernel(const int* __restrict__ in,
                                                    int* __restrict__ tmp,
                                                    int* __restrict__ bsums, int n) {
  __shared__ int sm[2][512];
  int t = threadIdx.x;
  int gid = blockIdx.x * 512 + t;
  int v = (gid < n) ? in[gid] : 0;
  int pp = 0;
  sm[0][t] = v;
  __syncthreads();
  for (int off = 1; off < 512; off <<= 1) {
    int nv = sm[pp][t];
    if (t >= off) nv += sm[pp][t - off];
    sm[pp ^ 1][t] = nv;
    pp ^= 1;
    __syncthreads();
  }
  int inc = sm[pp][t];
  if (gid < n) tmp[gid] = inc;
  if (t == 511) bsums[blockIdx.x] = inc;
}

__global__ __launch_bounds__(256) void scan2_kernel(int* bsums, int nb) {
  __shared__ int sm[2][256];
  int t = threadIdx.x;
  int v = (t < nb) ? bsums[t] : 0;
  int pp = 0;
  sm[0][t] = v;
  __syncthreads();
  for (int off = 1; off < 256; off <<= 1) {
    int nv = sm[pp][t];
    if (t >= off) nv += sm[pp][t - off];
    sm[pp ^ 1][t] = nv;
    pp ^= 1;
    __syncthreads();
  }
  int inc = sm[pp][t];
  if (t < nb) bsums[t] = inc - v;  // exclusive
}

// rowptr from scan, plus dinv = rsqrt(deg+1) fused here
__global__ __launch_bounds__(256) void scan3_kernel(const int* __restrict__ tmp,
                                                    const int* __restrict__ bsums,
                                                    const int* __restrict__ deg,
                                                    int* __restrict__ rowptr,
                                                    float* __restrict__ dinv, int n) {
  int gid = blockIdx.x * 256 + threadIdx.x;
  if (gid < n) {
    rowptr[gid + 1] = tmp[gid] + bsums[gid >> 9];
    dinv[gid] = rsqrtf((float)(deg[gid] + 1));  // +1 self loop
  }
  if (gid == 0) rowptr[0] = 0;
}

// CSR scatter: one int2 {src, eid} store per edge; 4 edges/thread for MLP.
__global__ __launch_bounds__(256) void scatter_kernel(const int* __restrict__ src,
                                                      const int* __restrict__ dst,
                                                      const int* __restrict__ rowptr,
                                                      int* __restrict__ cnt,
                                                      int2* __restrict__ csr, int E) {
  int base = blockIdx.x * 1024 + threadIdx.x;
#pragma unroll
  for (int i = 0; i < 4; ++i) {
    int e = base + i * 256;
    if (e < E) {
      int d = dst[e];
      int pos = rowptr[d] + atomicAdd(&cnt[d], 1);
      csr[pos] = make_int2(src[e], e);
    }
  }
}

// ---------- pack W[128][128] fp32 -> bf16 hi/lo in MFMA B-fragment order ----
// B frag (16x16x32): lane holds B[k=(lane>>4)*8+j][n=lane&15], j=0..7.
// Layout: Wp[half(0=hi,1=lo)][ct(8)][kf(4)][lane(64)][8] bf16.
__global__ __launch_bounds__(256) void wpack_kernel(const float* __restrict__ W,
                                                    short* __restrict__ Wp) {
  int t = blockIdx.x * 256 + threadIdx.x;  // 2048 = ct*256 + kf*64 + lane
  if (t >= 2048) return;
  int lane = t & 63;
  int kf = (t >> 6) & 3;
  int ct = t >> 8;
  int col = ct * 16 + (lane & 15);
  int k0 = kf * 32 + (lane >> 4) * 8;
  short* dh = Wp + ((((0 * 8 + ct) * 4 + kf) * 64) + lane) * 8;
  short* dl = Wp + ((((1 * 8 + ct) * 4 + kf) * 64) + lane) * 8;
  for (int j = 0; j < 8; ++j) {
    float w = W[(k0 + j) * 128 + col];
    unsigned h = bf16_rne(w);
    float hf = __builtin_bit_cast(float, h << 16);
    unsigned lo = bf16_rne(w - hf);
    dh[j] = (short)h;
    dl[j] = (short)lo;
  }
}

// ---------- bf16 MFMA GEMM: out[r,:] = bf16( dinv[r] * (A[r,:] @ W) ) ----
// R17 structure (layer 1 only now): block = 64 rows x 128 cols, 4 waves,
// wave = 2 col-tiles, straight-line 4 stages, depth-1 A prefetch, four
// independent acc chains, zero-predicate fast path. ~57us, latency floor.
template <bool FP32A>
__global__ __launch_bounds__(256, 4) void gemm_kernel(const void* __restrict__ Av,
                                                      const short* __restrict__ Wp,
                                                      const float* __restrict__ dinv,
                                                      unsigned short* __restrict__ out,
                                                      int M) {
  const int tid = threadIdx.x;
  const int wave = tid >> 6;
  const int lane = tid & 63;
  const int quad = lane >> 4;
  const int l15 = lane & 15;

  const int ct0 = wave * 2;
  const int ct1 = wave * 2 + 1;
  const int colbase = wave * 32 + l15;
  const int rb0 = blockIdx.x * 64;

  float4 rawf[4][8];
  short8 rawb[4][4];
  const short8 s8z = {0, 0, 0, 0, 0, 0, 0, 0};
  const short8* Wp8 = (const short8*)Wp;

  auto issue = [&](int t) {
    const int arow = rb0 + t * 16 + l15;
    if constexpr (FP32A) {
      const float4* A4 = (const float4*)Av + (size_t)arow * 32;
#pragma unroll
      for (int u = 0; u < 8; ++u) rawf[t][u] = A4[(u >> 1) * 8 + quad * 2 + (u & 1)];
    } else {
      const unsigned short* A2 = (const unsigned short*)Av + (size_t)arow * 128;
#pragma unroll
      for (int f = 0; f < 4; ++f) rawb[t][f] = *(const short8*)(A2 + f * 32 + quad * 8);
    }
  };
  auto convert = [&](int t, short8 (&af)[4]) {
    if constexpr (FP32A) {
#pragma unroll
      for (int f = 0; f < 4; ++f) {
        const float4 a0 = rawf[t][f * 2];
        const float4 a1 = rawf[t][f * 2 + 1];
        const float av[8] = {a0.x, a0.y, a0.z, a0.w, a1.x, a1.y, a1.z, a1.w};
#pragma unroll
        for (int j = 0; j < 8; ++j) af[f][j] = (short)bf16_rne(av[j]);
      }
    } else {
#pragma unroll
      for (int f = 0; f < 4; ++f) af[f] = rawb[t][f];
    }
  };

  if (rb0 + 64 <= M) {
    issue(0);
#pragma unroll
    for (int t = 0; t < 4; ++t) {
      if (t < 3) issue(t + 1);
      const f32x4 dv = *(const f32x4*)(dinv + rb0 + t * 16 + quad * 4);
      short8 af[4];
      convert(t, af);
      f32x4 a0h = {0.f, 0.f, 0.f, 0.f};
      f32x4 a0l = {0.f, 0.f, 0.f, 0.f};
      f32x4 a1h = {0.f, 0.f, 0.f, 0.f};
      f32x4 a1l = {0.f, 0.f, 0.f, 0.f};
#pragma unroll
      for (int f = 0; f < 4; ++f) {
        const short8 bh0 = Wp8[((0 * 8 + ct0) * 4 + f) * 64 + lane];
        const short8 bh1 = Wp8[((0 * 8 + ct1) * 4 + f) * 64 + lane];
        const short8 bl0 = Wp8[((1 * 8 + ct0) * 4 + f) * 64 + lane];
        const short8 bl1 = Wp8[((1 * 8 + ct1) * 4 + f) * 64 + lane];
        a0h = __builtin_amdgcn_mfma_f32_16x16x32_bf16(af[f], bh0, a0h, 0, 0, 0);
        a1h = __builtin_amdgcn_mfma_f32_16x16x32_bf16(af[f], bh1, a1h, 0, 0, 0);
        a0l = __builtin_amdgcn_mfma_f32_16x16x32_bf16(af[f], bl0, a0l, 0, 0, 0);
        a1l = __builtin_amdgcn_mfma_f32_16x16x32_bf16(af[f], bl1, a1l, 0, 0, 0);
      }
#pragma unroll
      for (int i = 0; i < 4; ++i) {
        const int r = rb0 + t * 16 + quad * 4 + i;
        out[(size_t)r * 128 + colbase] =
            (unsigned short)bf16_rne((a0h[i] + a0l[i]) * dv[i]);
        out[(size_t)r * 128 + colbase + 16] =
            (unsigned short)bf16_rne((a1h[i] + a1l[i]) * dv[i]);
      }
    }
  } else {
#pragma unroll 1
    for (int t = 0; t < 4; ++t) {
      const int rb = rb0 + t * 16;
      if (rb >= M) break;
      const int arow = rb + l15;
      const bool rok = arow < M;
      short8 af[4];
      if constexpr (FP32A) {
        const float4* A4 = (const float4*)Av + (size_t)arow * 32;
#pragma unroll
        for (int f = 0; f < 4; ++f) {
          if (rok) {
            float4 a0 = A4[f * 8 + quad * 2];
            float4 a1 = A4[f * 8 + quad * 2 + 1];
            float av[8] = {a0.x, a0.y, a0.z, a0.w, a1.x, a1.y, a1.z, a1.w};
#pragma unroll
            for (int j = 0; j < 8; ++j) af[f][j] = (short)bf16_rne(av[j]);
          } else {
            af[f] = s8z;
          }
        }
      } else {
        const unsigned short* A2 = (const unsigned short*)Av + (size_t)arow * 128;
#pragma unroll
        for (int f = 0; f < 4; ++f)
          af[f] = rok ? *(const short8*)(A2 + f * 32 + quad * 8) : s8z;
      }
      f32x4 a0h = {0.f, 0.f, 0.f, 0.f};
      f32x4 a0l = {0.f, 0.f, 0.f, 0.f};
      f32x4 a1h = {0.f, 0.f, 0.f, 0.f};
      f32x4 a1l = {0.f, 0.f, 0.f, 0.f};
#pragma unroll
      for (int f = 0; f < 4; ++f) {
        const short8 bh0 = Wp8[((0 * 8 + ct0) * 4 + f) * 64 + lane];
        const short8 bh1 = Wp8[((0 * 8 + ct1) * 4 + f) * 64 + lane];
        const short8 bl0 = Wp8[((1 * 8 + ct0) * 4 + f) * 64 + lane];
        const short8 bl1 = Wp8[((1 * 8 + ct1) * 4 + f) * 64 + lane];
        a0h = __builtin_amdgcn_mfma_f32_16x16x32_bf16(af[f], bh0, a0h, 0, 0, 0);
        a1h = __builtin_amdgcn_mfma_f32_16x16x32_bf16(af[f], bh1, a1h, 0, 0, 0);
        a0l = __builtin_amdgcn_mfma_f32_16x16x32_bf16(af[f], bl0, a0l, 0, 0, 0);
        a1l = __builtin_amdgcn_mfma_f32_16x16x32_bf16(af[f], bl1, a1l, 0, 0, 0);
      }
#pragma unroll
      for (int i = 0; i < 4; ++i) {
        const int r = rb + quad * 4 + i;
        if (r < M) {
          const float d = dinv[r];
          out[(size_t)r * 128 + colbase] =
              (unsigned short)bf16_rne((a0h[i] + a0l[i]) * d);
          out[(size_t)r * 128 + colbase + 16] =
              (unsigned short)bf16_rne((a1h[i] + a1l[i]) * d);
        }
      }
    }
  }
}

// ---------- FUSED agg1 + gemm2 ----------
// Phase 1 (per node, 16 lanes): z1 = relu(dinv*(xw_self + sum_nbr xw) + b1),
//   bf16 rows into 4KB LDS tile (chunk index XOR row -> conflict-free reads).
// Phase 2 (per wave): 16x128 z1-tile @ 128x128 W2 via MFMA, wave = 2
//   col-tiles x hi/lo; out = bf16(dinv[r] * (z1@W2)[r,:]).
// Removes the standalone gemm2 dispatch and the z1 global round-trip.
__global__ __launch_bounds__(256) void agg_gemm_kernel(
    const unsigned short* __restrict__ xw, const float* __restrict__ dinv,
    const int* __restrict__ rowptr, const int2* __restrict__ csr,
    const float* __restrict__ bias, const short* __restrict__ Wp,
    unsigned short* __restrict__ out, int N) {
  __shared__ short8 z1t[16][16];  // [row][chunk ^ row], 4 KB

  const int tid = threadIdx.x;
  const int node0 = blockIdx.x * 16;
  const int n = tid >> 4;  // local node 0..15
  const int l = tid & 15;  // chunk lane 0..15
  const int node = node0 + n;

  // ---- phase 1: aggregation (no early return: barrier below) ----
  short8 o = {0, 0, 0, 0, 0, 0, 0, 0};
  if (node < N) {
    const short8* xw8 = (const short8*)xw;
    short8 sv = xw8[(size_t)node * 16 + l];
    float acc[8];
#pragma unroll
    for (int j = 0; j < 8; ++j) acc[j] = bf2f((unsigned short)sv[j]);
    int s = rowptr[node], e = rowptr[node + 1];
    int k = s;
    for (; k + 4 <= e; k += 4) {
      int j0 = csr[k].x, j1 = csr[k + 1].x, j2 = csr[k + 2].x, j3 = csr[k + 3].x;
      short8 v0 = xw8[(size_t)j0 * 16 + l];
      short8 v1 = xw8[(size_t)j1 * 16 + l];
      short8 v2 = xw8[(size_t)j2 * 16 + l];
      short8 v3 = xw8[(size_t)j3 * 16 + l];
#pragma unroll
      for (int j = 0; j < 8; ++j) {
        acc[j] += (bf2f((unsigned short)v0[j]) + bf2f((unsigned short)v1[j])) +
                  (bf2f((unsigned short)v2[j]) + bf2f((unsigned short)v3[j]));
      }
    }
    for (; k < e; ++k) {
      short8 v = xw8[(size_t)csr[k].x * 16 + l];
#pragma unroll
      for (int j = 0; j < 8; ++j) acc[j] += bf2f((unsigned short)v[j]);
    }
    float di = dinv[node];
    const float4* b4 = (const float4*)bias;
    float4 bb0 = b4[l * 2], bb1 = b4[l * 2 + 1];
    float bv[8] = {bb0.x, bb0.y, bb0.z, bb0.w, bb1.x, bb1.y, bb1.z, bb1.w};
#pragma unroll
    for (int j = 0; j < 8; ++j) {
      float v = fmaf(di, acc[j], bv[j]);
      v = fmaxf(v, 0.f);  // relu (layer 1)
      o[j] = (short)bf16_rne(v);
    }
  }
  z1t[n][l ^ n] = o;  // swizzled store
  __syncthreads();

  // ---- phase 2: MFMA 16x128 @ 128x128 ----
  const int wave = tid >> 6;
  const int lane = tid & 63;
  const int quad = lane >> 4;
  const int l15 = lane & 15;
  const int ct0 = wave * 2;
  const int ct1 = wave * 2 + 1;

  short8 af[4];  // A frag: lane holds z1[m=l15][k=f*32+quad*8 .. +7]
#pragma unroll
  for (int f = 0; f < 4; ++f) af[f] = z1t[l15][(f * 4 + quad) ^ l15];

  const short8* Wp8 = (const short8*)Wp;
  f32x4 a0h = {0.f, 0.f, 0.f, 0.f};
  f32x4 a0l = {0.f, 0.f, 0.f, 0.f};
  f32x4 a1h = {0.f, 0.f, 0.f, 0.f};
  f32x4 a1l = {0.f, 0.f, 0.f, 0.f};
#pragma unroll
  for (int f = 0; f < 4; ++f) {
    const short8 bh0 = Wp8[((0 * 8 + ct0) * 4 + f) * 64 + lane];
    const short8 bh1 = Wp8[((0 * 8 + ct1) * 4 + f) * 64 + lane];
    const short8 bl0 = Wp8[((1 * 8 + ct0) * 4 + f) * 64 + lane];
    const short8 bl1 = Wp8[((1 * 8 + ct1) * 4 + f) * 64 + lane];
    a0h = __builtin_amdgcn_mfma_f32_16x16x32_bf16(af[f], bh0, a0h, 0, 0, 0);
    a1h = __builtin_amdgcn_mfma_f32_16x16x32_bf16(af[f], bh1, a1h, 0, 0, 0);
    a0l = __builtin_amdgcn_mfma_f32_16x16x32_bf16(af[f], bl0, a0l, 0, 0, 0);
    a1l = __builtin_amdgcn_mfma_f32_16x16x32_bf16(af[f], bl1, a1l, 0, 0, 0);
  }

  // epilogue: C/D layout col=lane&15, row=quad*4+i; out = dinv[r]*(z1@W2)
  if (node0 + 16 <= N) {
    const f32x4 dv = *(const f32x4*)(dinv + node0 + quad * 4);
#pragma unroll
    for (int i = 0; i < 4; ++i) {
      const int r = node0 + quad * 4 + i;
      out[(size_t)r * 128 + ct0 * 16 + l15] =
          (unsigned short)bf16_rne((a0h[i] + a0l[i]) * dv[i]);
      out[(size_t)r * 128 + ct1 * 16 + l15] =
          (unsigned short)bf16_rne((a1h[i] + a1l[i]) * dv[i]);
    }
  } else {
#pragma unroll
    for (int i = 0; i < 4; ++i) {
      const int r = node0 + quad * 4 + i;
      if (r < N) {
        const float d = dinv[r];
        out[(size_t)r * 128 + ct0 * 16 + l15] =
            (unsigned short)bf16_rne((a0h[i] + a0l[i]) * d);
        out[(size_t)r * 128 + ct1 * 16 + l15] =
            (unsigned short)bf16_rne((a1h[i] + a1l[i]) * d);
      }
    }
  }
}

// ---------- aggregation over prescaled bf16 rows (layer 2) ----------
__global__ __launch_bounds__(256) void agg_kernel(const unsigned short* __restrict__ xw,
                                                  const float* __restrict__ dinv,
                                                  const int* __restrict__ rowptr,
                                                  const int2* __restrict__ csr,
                                                  const float* __restrict__ bias,
                                                  unsigned short* __restrict__ out,
                                                  int relu, int N) {
  int node = blockIdx.x * 16 + (threadIdx.x >> 4);
  int l = threadIdx.x & 15;
  if (node >= N) return;
  const short8* xw8 = (const short8*)xw;  // row = 16 short8 groups
  short8 sv = xw8[(size_t)node * 16 + l];
  float acc[8];
#pragma unroll
  for (int j = 0; j < 8; ++j) acc[j] = bf2f((unsigned short)sv[j]);
  int s = rowptr[node], e = rowptr[node + 1];
  int k = s;
  for (; k + 4 <= e; k += 4) {
    int j0 = csr[k].x, j1 = csr[k + 1].x, j2 = csr[k + 2].x, j3 = csr[k + 3].x;
    short8 v0 = xw8[(size_t)j0 * 16 + l];
    short8 v1 = xw8[(size_t)j1 * 16 + l];
    short8 v2 = xw8[(size_t)j2 * 16 + l];
    short8 v3 = xw8[(size_t)j3 * 16 + l];
#pragma unroll
    for (int j = 0; j < 8; ++j) {
      acc[j] += (bf2f((unsigned short)v0[j]) + bf2f((unsigned short)v1[j])) +
                (bf2f((unsigned short)v2[j]) + bf2f((unsigned short)v3[j]));
    }
  }
  for (; k < e; ++k) {
    short8 v = xw8[(size_t)csr[k].x * 16 + l];
#pragma unroll
    for (int j = 0; j < 8; ++j) acc[j] += bf2f((unsigned short)v[j]);
  }
  float di = dinv[node];
  const float4* b4 = (const float4*)bias;
  float4 bb0 = b4[l * 2], bb1 = b4[l * 2 + 1];
  float bv[8] = {bb0.x, bb0.y, bb0.z, bb0.w, bb1.x, bb1.y, bb1.z, bb1.w};
  short8 o;
#pragma unroll
  for (int j = 0; j < 8; ++j) {
    float v = fmaf(di, acc[j], bv[j]);
    if (relu) v = fmaxf(v, 0.f);
    o[j] = (short)bf16_rne(v);
  }
  ((short8*)out)[(size_t)node * 16 + l] = o;
}

// ---------- decode over dst-CSR, bf16 z2: 16 lanes/node ----------
__global__ __launch_bounds__(256) void decode_kernel(const unsigned short* __restrict__ z,
                                                     const int* __restrict__ rowptr,
                                                     const int2* __restrict__ csr,
                                                     float* __restrict__ out, int N) {
  int node = blockIdx.x * 16 + (threadIdx.x >> 4);
  int l = threadIdx.x & 15;
  if (node >= N) return;
  const short8* z8 = (const short8*)z;
  short8 zv = z8[(size_t)node * 16 + l];
  float zd[8];
#pragma unroll
  for (int j = 0; j < 8; ++j) zd[j] = bf2f((unsigned short)zv[j]);
  int s = rowptr[node], e = rowptr[node + 1];
  int k = s;
  for (; k + 4 <= e; k += 4) {
    int2 c0 = csr[k], c1 = csr[k + 1], c2 = csr[k + 2], c3 = csr[k + 3];
    short8 v0 = z8[(size_t)c0.x * 16 + l];
    short8 v1 = z8[(size_t)c1.x * 16 + l];
    short8 v2 = z8[(size_t)c2.x * 16 + l];
    short8 v3 = z8[(size_t)c3.x * 16 + l];
    float p0 = 0.f, p1 = 0.f, p2 = 0.f, p3 = 0.f;
#pragma unroll
    for (int j = 0; j < 8; ++j) {
      p0 = fmaf(zd[j], bf2f((unsigned short)v0[j]), p0);
      p1 = fmaf(zd[j], bf2f((unsigned short)v1[j]), p1);
      p2 = fmaf(zd[j], bf2f((unsigned short)v2[j]), p2);
      p3 = fmaf(zd[j], bf2f((unsigned short)v3[j]), p3);
    }
#pragma unroll
    for (int off = 8; off > 0; off >>= 1) {
      p0 += __shfl_xor(p0, off);
      p1 += __shfl_xor(p1, off);
      p2 += __shfl_xor(p2, off);
      p3 += __shfl_xor(p3, off);
    }
    if (l == 0) {
      out[c0.y] = p0;
      out[c1.y] = p1;
      out[c2.y] = p2;
      out[c3.y] = p3;
    }
  }
  for (; k < e; ++k) {
    int2 c = csr[k];
    short8 v = z8[(size_t)c.x * 16 + l];
    float p = 0.f;
#pragma unroll
    for (int j = 0; j < 8; ++j) p = fmaf(zd[j], bf2f((unsigned short)v[j]), p);
#pragma unroll
    for (int off = 8; off > 0; off >>= 1) p += __shfl_xor(p, off);
    if (l == 0) out[c.y] = p;
  }
}

extern "C" void kernel_launch(void* const* d_in, const int* in_sizes, int n_in,
                              void* d_out, int out_size, void* d_ws, size_t ws_size,
                              hipStream_t stream) {
  const float* x  = (const float*)d_in[0];
  const int*   ei = (const int*)d_in[1];
  const float* W1 = (const float*)d_in[2];
  const float* b1 = (const float*)d_in[3];
  const float* W2 = (const float*)d_in[4];
  const float* b2 = (const float*)d_in[5];

  const int N = in_sizes[0] / 128;
  const int E = in_sizes[1] / 2;
  const int* src = ei;
  const int* dst = ei + E;

  char* ws = (char*)d_ws;
  size_t off = 0;
  auto alloc = [&](size_t bytes) -> void* {
    void* p = ws + off;
    off += (bytes + 255) & ~(size_t)255;
    return p;
  };
  unsigned short* bufA = (unsigned short*)alloc((size_t)N * 128 * 2);
  unsigned short* bufB = (unsigned short*)alloc((size_t)N * 128 * 2);
  float* dinv    = (float*)alloc((size_t)N * 4);
  int*   rowptr  = (int*)alloc((size_t)(N + 1) * 4);
  int2*  csr     = (int2*)alloc((size_t)E * 8);
  short* Wp1     = (short*)alloc((size_t)2 * 8 * 4 * 64 * 8 * 2);
  short* Wp2     = (short*)alloc((size_t)2 * 8 * 4 * 64 * 8 * 2);
  int*   tmp     = (int*)alloc((size_t)N * 4);
  int*   deg     = (int*)alloc((size_t)N * 4);   // zeroed region starts here
  int*   cnt     = (int*)alloc((size_t)N * 4);
  int*   bsums   = (int*)alloc(1024);
  size_t zbytes = ((char*)bsums + 1024) - (char*)deg;
  hipMemsetAsync(deg, 0, zbytes, stream);

  const int E4B = (E + 1023) / 1024;
  const int NB = (N + 255) / 256;
  const int SB = (N + 511) / 512;

  // W packing (independent of graph prep)
  wpack_kernel<<<8, 256, 0, stream>>>(W1, Wp1);
  wpack_kernel<<<8, 256, 0, stream>>>(W2, Wp2);

  deg_kernel<<<E4B, 256, 0, stream>>>(dst, deg, E);
  scan1_kernel<<<SB, 512, 0, stream>>>(deg, tmp, bsums, N);
  scan2_kernel<<<1, 256, 0, stream>>>(bsums, SB);
  scan3_kernel<<<NB, 256, 0, stream>>>(tmp, bsums, deg, rowptr, dinv, N);
  scatter_kernel<<<E4B, 256, 0, stream>>>(src, dst, rowptr, cnt, csr, E);

  const int GB = (N + 63) / 64;
  const int AB = (N + 15) / 16;
  const int DB = (N + 15) / 16;

  // layer 1 GEMM (A = x, fp32 -> bf16 in-register): bufA = dinv*(x@W1)
  gemm_kernel<true><<<GB, 256, 0, stream>>>(x, Wp1, dinv, bufA, N);
  // FUSED: agg layer1 (+b1, relu) -> z1 in LDS -> MFMA z1@W2:
  //   bufB = dinv*(z1@W2)   (z1 never touches global memory)
  agg_gemm_kernel<<<AB, 256, 0, stream>>>(bufA, dinv, rowptr, csr, b1, Wp2,
                                          bufB, N);
  // layer 2 aggregation: bufA = z2 = dinv*(sum)+self + b2
  agg_kernel<<<AB, 256, 0, stream>>>(bufB, dinv, rowptr, csr, b2, bufA, 0, N);
  // decode over dst-CSR
  decode_kernel<<<DB, 256, 0, stream>>>(bufA, rowptr, csr, (float*)d_out, N);
}

// Round 9
// 304.160 us; speedup vs baseline: 1.1890x; 1.0308x over previous
//
#include <hip/hip_runtime.h>

// GCN link predictor: z1 = relu(GCNConv(x,W1,b1)); z2 = GCNConv(z1,W2,b2);
// out[e] = dot(z2[src[e]], z2[dst[e]])
// R9-R17: gemm restructuring history — 64-row-block forms are latency-bound
//   at 50-130us; compiler refuses register residency for W/prefetch (5x).
// R18 WIN (333->313.5): fused gemm2 into agg1 (16-node agg block = one M=16
//   MFMA tile; z1 via 4KB swizzled LDS; z1 never touches global). The fused
//   MFMA phase is invisible in the profile — gather-bound kernel absorbs it.
// R19: rewrite gemm1 in the PROVEN M=16-tile geometry (agg_gemm phase 2):
//   one block = 16 rows, grid 6250, straight-line single stage, 4 waves x
//   (2 col-tiles x hi/lo x 4kf = 16 MFMAs), redundant A-tile read per wave
//   (L1 broadcast). 4x blocks, 1/4 serial depth vs the 64-row form.

typedef __attribute__((ext_vector_type(8))) short short8;  // 8 bf16 = 4 VGPRs
typedef __attribute__((ext_vector_type(4))) float f32x4;

__device__ __forceinline__ unsigned bf16_rne(float x) {
  unsigned u = __builtin_bit_cast(unsigned, x);
  return (u + 0x7FFFu + ((u >> 16) & 1u)) >> 16;
}
__device__ __forceinline__ float bf2f(unsigned short u) {
  return __builtin_bit_cast(float, ((unsigned)u) << 16);
}

// ---------- degree: 4 edges/thread ----------
__global__ __launch_bounds__(256) void deg_kernel(const int* __restrict__ dst,
                                                  int* __restrict__ deg, int E) {
  int base = blockIdx.x * 1024 + threadIdx.x;
#pragma unroll
  for (int i = 0; i < 4; ++i) {
    int e = base + i * 256;
    if (e < E) atomicAdd(&deg[dst[e]], 1);
  }
}

// ---------- block scan (512 elems/block) ----------
__global__ __launch_bounds__(512) void scan1_kernel(const int* __restrict__ in,
                                                    int* __restrict__ tmp,
                                                    int* __restrict__ bsums, int n) {
  __shared__ int sm[2][512];
  int t = threadIdx.x;
  int gid = blockIdx.x * 512 + t;
  int v = (gid < n) ? in[gid] : 0;
  int pp = 0;
  sm[0][t] = v;
  __syncthreads();
  for (int off = 1; off < 512; off <<= 1) {
    int nv = sm[pp][t];
    if (t >= off) nv += sm[pp][t - off];
    sm[pp ^ 1][t] = nv;
    pp ^= 1;
    __syncthreads();
  }
  int inc = sm[pp][t];
  if (gid < n) tmp[gid] = inc;
  if (t == 511) bsums[blockIdx.x] = inc;
}

__global__ __launch_bounds__(256) void scan2_kernel(int* bsums, int nb) {
  __shared__ int sm[2][256];
  int t = threadIdx.x;
  int v = (t < nb) ? bsums[t] : 0;
  int pp = 0;
  sm[0][t] = v;
  __syncthreads();
  for (int off = 1; off < 256; off <<= 1) {
    int nv = sm[pp][t];
    if (t >= off) nv += sm[pp][t - off];
    sm[pp ^ 1][t] = nv;
    pp ^= 1;
    __syncthreads();
  }
  int inc = sm[pp][t];
  if (t < nb) bsums[t] = inc - v;  // exclusive
}

// rowptr from scan, plus dinv = rsqrt(deg+1) fused here
__global__ __launch_bounds__(256) void scan3_kernel(const int* __restrict__ tmp,
                                                    const int* __restrict__ bsums,
                                                    const int* __restrict__ deg,
                                                    int* __restrict__ rowptr,
                                                    float* __restrict__ dinv, int n) {
  int gid = blockIdx.x * 256 + threadIdx.x;
  if (gid < n) {
    rowptr[gid + 1] = tmp[gid] + bsums[gid >> 9];
    dinv[gid] = rsqrtf((float)(deg[gid] + 1));  // +1 self loop
  }
  if (gid == 0) rowptr[0] = 0;
}

// CSR scatter: one int2 {src, eid} store per edge; 4 edges/thread for MLP.
__global__ __launch_bounds__(256) void scatter_kernel(const int* __restrict__ src,
                                                      const int* __restrict__ dst,
                                                      const int* __restrict__ rowptr,
                                                      int* __restrict__ cnt,
                                                      int2* __restrict__ csr, int E) {
  int base = blockIdx.x * 1024 + threadIdx.x;
#pragma unroll
  for (int i = 0; i < 4; ++i) {
    int e = base + i * 256;
    if (e < E) {
      int d = dst[e];
      int pos = rowptr[d] + atomicAdd(&cnt[d], 1);
      csr[pos] = make_int2(src[e], e);
    }
  }
}

// ---------- pack W[128][128] fp32 -> bf16 hi/lo in MFMA B-fragment order ----
// B frag (16x16x32): lane holds B[k=(lane>>4)*8+j][n=lane&15], j=0..7.
// Layout: Wp[half(0=hi,1=lo)][ct(8)][kf(4)][lane(64)][8] bf16.
__global__ __launch_bounds__(256) void wpack_kernel(const float* __restrict__ W,
                                                    short* __restrict__ Wp) {
  int t = blockIdx.x * 256 + threadIdx.x;  // 2048 = ct*256 + kf*64 + lane
  if (t >= 2048) return;
  int lane = t & 63;
  int kf = (t >> 6) & 3;
  int ct = t >> 8;
  int col = ct * 16 + (lane & 15);
  int k0 = kf * 32 + (lane >> 4) * 8;
  short* dh = Wp + ((((0 * 8 + ct) * 4 + kf) * 64) + lane) * 8;
  short* dl = Wp + ((((1 * 8 + ct) * 4 + kf) * 64) + lane) * 8;
  for (int j = 0; j < 8; ++j) {
    float w = W[(k0 + j) * 128 + col];
    unsigned h = bf16_rne(w);
    float hf = __builtin_bit_cast(float, h << 16);
    unsigned lo = bf16_rne(w - hf);
    dh[j] = (short)h;
    dl[j] = (short)lo;
  }
}

// ---------- layer-1 GEMM, M=16-tile form: out[r,:] = bf16(dinv[r]*(x@W1)) --
// Grid ceil(M/16). Block = 16 rows x 128 cols. Each wave loads the SAME
// 16x512B fp32 A-tile (L1 broadcast), converts to bf16 frags in-register,
// then 2 col-tiles x hi/lo x 4kf = 16 MFMAs, scale by dinv, store bf16.
// Straight-line, single stage, no LDS, no barrier.
__global__ __launch_bounds__(256, 4) void gemm1_kernel(const float* __restrict__ A,
                                                       const short* __restrict__ Wp,
                                                       const float* __restrict__ dinv,
                                                       unsigned short* __restrict__ out,
                                                       int M) {
  const int tid = threadIdx.x;
  const int wave = tid >> 6;
  const int lane = tid & 63;
  const int quad = lane >> 4;
  const int l15 = lane & 15;
  const int ct0 = wave * 2;
  const int ct1 = wave * 2 + 1;
  const int colbase = wave * 32 + l15;
  const int rb0 = blockIdx.x * 16;
  const short8* Wp8 = (const short8*)Wp;

  if (rb0 + 16 <= M) {
    // ---- fast path: zero predicates ----
    const float4* A4 = (const float4*)A + (size_t)(rb0 + l15) * 32;
    float4 raw[8];
#pragma unroll
    for (int u = 0; u < 8; ++u) raw[u] = A4[(u >> 1) * 8 + quad * 2 + (u & 1)];
    const f32x4 dv = *(const f32x4*)(dinv + rb0 + quad * 4);

    short8 af[4];
#pragma unroll
    for (int f = 0; f < 4; ++f) {
      const float4 a0 = raw[f * 2];
      const float4 a1 = raw[f * 2 + 1];
      const float av[8] = {a0.x, a0.y, a0.z, a0.w, a1.x, a1.y, a1.z, a1.w};
#pragma unroll
      for (int j = 0; j < 8; ++j) af[f][j] = (short)bf16_rne(av[j]);
    }

    f32x4 a0h = {0.f, 0.f, 0.f, 0.f};
    f32x4 a0l = {0.f, 0.f, 0.f, 0.f};
    f32x4 a1h = {0.f, 0.f, 0.f, 0.f};
    f32x4 a1l = {0.f, 0.f, 0.f, 0.f};
#pragma unroll
    for (int f = 0; f < 4; ++f) {
      const short8 bh0 = Wp8[((0 * 8 + ct0) * 4 + f) * 64 + lane];
      const short8 bh1 = Wp8[((0 * 8 + ct1) * 4 + f) * 64 + lane];
      const short8 bl0 = Wp8[((1 * 8 + ct0) * 4 + f) * 64 + lane];
      const short8 bl1 = Wp8[((1 * 8 + ct1) * 4 + f) * 64 + lane];
      a0h = __builtin_amdgcn_mfma_f32_16x16x32_bf16(af[f], bh0, a0h, 0, 0, 0);
      a1h = __builtin_amdgcn_mfma_f32_16x16x32_bf16(af[f], bh1, a1h, 0, 0, 0);
      a0l = __builtin_amdgcn_mfma_f32_16x16x32_bf16(af[f], bl0, a0l, 0, 0, 0);
      a1l = __builtin_amdgcn_mfma_f32_16x16x32_bf16(af[f], bl1, a1l, 0, 0, 0);
    }
#pragma unroll
    for (int i = 0; i < 4; ++i) {
      const int r = rb0 + quad * 4 + i;
      out[(size_t)r * 128 + colbase] =
          (unsigned short)bf16_rne((a0h[i] + a0l[i]) * dv[i]);
      out[(size_t)r * 128 + colbase + 16] =
          (unsigned short)bf16_rne((a1h[i] + a1l[i]) * dv[i]);
    }
  } else {
    // ---- tail path: fully guarded (unused when M%16==0) ----
    const int arow = rb0 + l15;
    const bool rok = arow < M;
    const short8 s8z = {0, 0, 0, 0, 0, 0, 0, 0};
    short8 af[4];
    const float4* A4 = (const float4*)A + (size_t)arow * 32;
#pragma unroll
    for (int f = 0; f < 4; ++f) {
      if (rok) {
        float4 a0 = A4[f * 8 + quad * 2];
        float4 a1 = A4[f * 8 + quad * 2 + 1];
        float av[8] = {a0.x, a0.y, a0.z, a0.w, a1.x, a1.y, a1.z, a1.w};
#pragma unroll
        for (int j = 0; j < 8; ++j) af[f][j] = (short)bf16_rne(av[j]);
      } else {
        af[f] = s8z;
      }
    }
    f32x4 a0h = {0.f, 0.f, 0.f, 0.f};
    f32x4 a0l = {0.f, 0.f, 0.f, 0.f};
    f32x4 a1h = {0.f, 0.f, 0.f, 0.f};
    f32x4 a1l = {0.f, 0.f, 0.f, 0.f};
#pragma unroll
    for (int f = 0; f < 4; ++f) {
      const short8 bh0 = Wp8[((0 * 8 + ct0) * 4 + f) * 64 + lane];
      const short8 bh1 = Wp8[((0 * 8 + ct1) * 4 + f) * 64 + lane];
      const short8 bl0 = Wp8[((1 * 8 + ct0) * 4 + f) * 64 + lane];
      const short8 bl1 = Wp8[((1 * 8 + ct1) * 4 + f) * 64 + lane];
      a0h = __builtin_amdgcn_mfma_f32_16x16x32_bf16(af[f], bh0, a0h, 0, 0, 0);
      a1h = __builtin_amdgcn_mfma_f32_16x16x32_bf16(af[f], bh1, a1h, 0, 0, 0);
      a0l = __builtin_amdgcn_mfma_f32_16x16x32_bf16(af[f], bl0, a0l, 0, 0, 0);
      a1l = __builtin_amdgcn_mfma_f32_16x16x32_bf16(af[f], bl1, a1l, 0, 0, 0);
    }
#pragma unroll
    for (int i = 0; i < 4; ++i) {
      const int r = rb0 + quad * 4 + i;
      if (r < M) {
        const float d = dinv[r];
        out[(size_t)r * 128 + colbase] =
            (unsigned short)bf16_rne((a0h[i] + a0l[i]) * d);
        out[(size_t)r * 128 + colbase + 16] =
            (unsigned short)bf16_rne((a1h[i] + a1l[i]) * d);
      }
    }
  }
}

// ---------- FUSED agg1 + gemm2 ----------
// Phase 1 (per node, 16 lanes): z1 = relu(dinv*(xw_self + sum_nbr xw) + b1),
//   bf16 rows into 4KB LDS tile (chunk index XOR row -> conflict-free reads).
// Phase 2 (per wave): 16x128 z1-tile @ 128x128 W2 via MFMA, wave = 2
//   col-tiles x hi/lo; out = bf16(dinv[r] * (z1@W2)[r,:]).
__global__ __launch_bounds__(256) void agg_gemm_kernel(
    const unsigned short* __restrict__ xw, const float* __restrict__ dinv,
    const int* __restrict__ rowptr, const int2* __restrict__ csr,
    const float* __restrict__ bias, const short* __restrict__ Wp,
    unsigned short* __restrict__ out, int N) {
  __shared__ short8 z1t[16][16];  // [row][chunk ^ row], 4 KB

  const int tid = threadIdx.x;
  const int node0 = blockIdx.x * 16;
  const int n = tid >> 4;  // local node 0..15
  const int l = tid & 15;  // chunk lane 0..15
  const int node = node0 + n;

  // ---- phase 1: aggregation (no early return: barrier below) ----
  short8 o = {0, 0, 0, 0, 0, 0, 0, 0};
  if (node < N) {
    const short8* xw8 = (const short8*)xw;
    short8 sv = xw8[(size_t)node * 16 + l];
    float acc[8];
#pragma unroll
    for (int j = 0; j < 8; ++j) acc[j] = bf2f((unsigned short)sv[j]);
    int s = rowptr[node], e = rowptr[node + 1];
    int k = s;
    for (; k + 4 <= e; k += 4) {
      int j0 = csr[k].x, j1 = csr[k + 1].x, j2 = csr[k + 2].x, j3 = csr[k + 3].x;
      short8 v0 = xw8[(size_t)j0 * 16 + l];
      short8 v1 = xw8[(size_t)j1 * 16 + l];
      short8 v2 = xw8[(size_t)j2 * 16 + l];
      short8 v3 = xw8[(size_t)j3 * 16 + l];
#pragma unroll
      for (int j = 0; j < 8; ++j) {
        acc[j] += (bf2f((unsigned short)v0[j]) + bf2f((unsigned short)v1[j])) +
                  (bf2f((unsigned short)v2[j]) + bf2f((unsigned short)v3[j]));
      }
    }
    for (; k < e; ++k) {
      short8 v = xw8[(size_t)csr[k].x * 16 + l];
#pragma unroll
      for (int j = 0; j < 8; ++j) acc[j] += bf2f((unsigned short)v[j]);
    }
    float di = dinv[node];
    const float4* b4 = (const float4*)bias;
    float4 bb0 = b4[l * 2], bb1 = b4[l * 2 + 1];
    float bv[8] = {bb0.x, bb0.y, bb0.z, bb0.w, bb1.x, bb1.y, bb1.z, bb1.w};
#pragma unroll
    for (int j = 0; j < 8; ++j) {
      float v = fmaf(di, acc[j], bv[j]);
      v = fmaxf(v, 0.f);  // relu (layer 1)
      o[j] = (short)bf16_rne(v);
    }
  }
  z1t[n][l ^ n] = o;  // swizzled store
  __syncthreads();

  // ---- phase 2: MFMA 16x128 @ 128x128 ----
  const int wave = tid >> 6;
  const int lane = tid & 63;
  const int quad = lane >> 4;
  const int l15 = lane & 15;
  const int ct0 = wave * 2;
  const int ct1 = wave * 2 + 1;

  short8 af[4];  // A frag: lane holds z1[m=l15][k=f*32+quad*8 .. +7]
#pragma unroll
  for (int f = 0; f < 4; ++f) af[f] = z1t[l15][(f * 4 + quad) ^ l15];

  const short8* Wp8 = (const short8*)Wp;
  f32x4 a0h = {0.f, 0.f, 0.f, 0.f};
  f32x4 a0l = {0.f, 0.f, 0.f, 0.f};
  f32x4 a1h = {0.f, 0.f, 0.f, 0.f};
  f32x4 a1l = {0.f, 0.f, 0.f, 0.f};
#pragma unroll
  for (int f = 0; f < 4; ++f) {
    const short8 bh0 = Wp8[((0 * 8 + ct0) * 4 + f) * 64 + lane];
    const short8 bh1 = Wp8[((0 * 8 + ct1) * 4 + f) * 64 + lane];
    const short8 bl0 = Wp8[((1 * 8 + ct0) * 4 + f) * 64 + lane];
    const short8 bl1 = Wp8[((1 * 8 + ct1) * 4 + f) * 64 + lane];
    a0h = __builtin_amdgcn_mfma_f32_16x16x32_bf16(af[f], bh0, a0h, 0, 0, 0);
    a1h = __builtin_amdgcn_mfma_f32_16x16x32_bf16(af[f], bh1, a1h, 0, 0, 0);
    a0l = __builtin_amdgcn_mfma_f32_16x16x32_bf16(af[f], bl0, a0l, 0, 0, 0);
    a1l = __builtin_amdgcn_mfma_f32_16x16x32_bf16(af[f], bl1, a1l, 0, 0, 0);
  }

  // epilogue: C/D layout col=lane&15, row=quad*4+i; out = dinv[r]*(z1@W2)
  if (node0 + 16 <= N) {
    const f32x4 dv = *(const f32x4*)(dinv + node0 + quad * 4);
#pragma unroll
    for (int i = 0; i < 4; ++i) {
      const int r = node0 + quad * 4 + i;
      out[(size_t)r * 128 + ct0 * 16 + l15] =
          (unsigned short)bf16_rne((a0h[i] + a0l[i]) * dv[i]);
      out[(size_t)r * 128 + ct1 * 16 + l15] =
          (unsigned short)bf16_rne((a1h[i] + a1l[i]) * dv[i]);
    }
  } else {
#pragma unroll
    for (int i = 0; i < 4; ++i) {
      const int r = node0 + quad * 4 + i;
      if (r < N) {
        const float d = dinv[r];
        out[(size_t)r * 128 + ct0 * 16 + l15] =
            (unsigned short)bf16_rne((a0h[i] + a0l[i]) * d);
        out[(size_t)r * 128 + ct1 * 16 + l15] =
            (unsigned short)bf16_rne((a1h[i] + a1l[i]) * d);
      }
    }
  }
}

// ---------- aggregation over prescaled bf16 rows (layer 2) ----------
__global__ __launch_bounds__(256) void agg_kernel(const unsigned short* __restrict__ xw,
                                                  const float* __restrict__ dinv,
                                                  const int* __restrict__ rowptr,
                                                  const int2* __restrict__ csr,
                                                  const float* __restrict__ bias,
                                                  unsigned short* __restrict__ out,
                                                  int relu, int N) {
  int node = blockIdx.x * 16 + (threadIdx.x >> 4);
  int l = threadIdx.x & 15;
  if (node >= N) return;
  const short8* xw8 = (const short8*)xw;  // row = 16 short8 groups
  short8 sv = xw8[(size_t)node * 16 + l];
  float acc[8];
#pragma unroll
  for (int j = 0; j < 8; ++j) acc[j] = bf2f((unsigned short)sv[j]);
  int s = rowptr[node], e = rowptr[node + 1];
  int k = s;
  for (; k + 4 <= e; k += 4) {
    int j0 = csr[k].x, j1 = csr[k + 1].x, j2 = csr[k + 2].x, j3 = csr[k + 3].x;
    short8 v0 = xw8[(size_t)j0 * 16 + l];
    short8 v1 = xw8[(size_t)j1 * 16 + l];
    short8 v2 = xw8[(size_t)j2 * 16 + l];
    short8 v3 = xw8[(size_t)j3 * 16 + l];
#pragma unroll
    for (int j = 0; j < 8; ++j) {
      acc[j] += (bf2f((unsigned short)v0[j]) + bf2f((unsigned short)v1[j])) +
                (bf2f((unsigned short)v2[j]) + bf2f((unsigned short)v3[j]));
    }
  }
  for (; k < e; ++k) {
    short8 v = xw8[(size_t)csr[k].x * 16 + l];
#pragma unroll
    for (int j = 0; j < 8; ++j) acc[j] += bf2f((unsigned short)v[j]);
  }
  float di = dinv[node];
  const float4* b4 = (const float4*)bias;
  float4 bb0 = b4[l * 2], bb1 = b4[l * 2 + 1];
  float bv[8] = {bb0.x, bb0.y, bb0.z, bb0.w, bb1.x, bb1.y, bb1.z, bb1.w};
  short8 o;
#pragma unroll
  for (int j = 0; j < 8; ++j) {
    float v = fmaf(di, acc[j], bv[j]);
    if (relu) v = fmaxf(v, 0.f);
    o[j] = (short)bf16_rne(v);
  }
  ((short8*)out)[(size_t)node * 16 + l] = o;
}

// ---------- decode over dst-CSR, bf16 z2: 16 lanes/node ----------
__global__ __launch_bounds__(256) void decode_kernel(const unsigned short* __restrict__ z,
                                                     const int* __restrict__ rowptr,
                                                     const int2* __restrict__ csr,
                                                     float* __restrict__ out, int N) {
  int node = blockIdx.x * 16 + (threadIdx.x >> 4);
  int l = threadIdx.x & 15;
  if (node >= N) return;
  const short8* z8 = (const short8*)z;
  short8 zv = z8[(size_t)node * 16 + l];
  float zd[8];
#pragma unroll
  for (int j = 0; j < 8; ++j) zd[j] = bf2f((unsigned short)zv[j]);
  int s = rowptr[node], e = rowptr[node + 1];
  int k = s;
  for (; k + 4 <= e; k += 4) {
    int2 c0 = csr[k], c1 = csr[k + 1], c2 = csr[k + 2], c3 = csr[k + 3];
    short8 v0 = z8[(size_t)c0.x * 16 + l];
    short8 v1 = z8[(size_t)c1.x * 16 + l];
    short8 v2 = z8[(size_t)c2.x * 16 + l];
    short8 v3 = z8[(size_t)c3.x * 16 + l];
    float p0 = 0.f, p1 = 0.f, p2 = 0.f, p3 = 0.f;
#pragma unroll
    for (int j = 0; j < 8; ++j) {
      p0 = fmaf(zd[j], bf2f((unsigned short)v0[j]), p0);
      p1 = fmaf(zd[j], bf2f((unsigned short)v1[j]), p1);
      p2 = fmaf(zd[j], bf2f((unsigned short)v2[j]), p2);
      p3 = fmaf(zd[j], bf2f((unsigned short)v3[j]), p3);
    }
#pragma unroll
    for (int off = 8; off > 0; off >>= 1) {
      p0 += __shfl_xor(p0, off);
      p1 += __shfl_xor(p1, off);
      p2 += __shfl_xor(p2, off);
      p3 += __shfl_xor(p3, off);
    }
    if (l == 0) {
      out[c0.y] = p0;
      out[c1.y] = p1;
      out[c2.y] = p2;
      out[c3.y] = p3;
    }
  }
  for (; k < e; ++k) {
    int2 c = csr[k];
    short8 v = z8[(size_t)c.x * 16 + l];
    float p = 0.f;
#pragma unroll
    for (int j = 0; j < 8; ++j) p = fmaf(zd[j], bf2f((unsigned short)v[j]), p);
#pragma unroll
    for (int off = 8; off > 0; off >>= 1) p += __shfl_xor(p, off);
    if (l == 0) out[c.y] = p;
  }
}

extern "C" void kernel_launch(void* const* d_in, const int* in_sizes, int n_in,
                              void* d_out, int out_size, void* d_ws, size_t ws_size,
                              hipStream_t stream) {
  const float* x  = (const float*)d_in[0];
  const int*   ei = (const int*)d_in[1];
  const float* W1 = (const float*)d_in[2];
  const float* b1 = (const float*)d_in[3];
  const float* W2 = (const float*)d_in[4];
  const float* b2 = (const float*)d_in[5];

  const int N = in_sizes[0] / 128;
  const int E = in_sizes[1] / 2;
  const int* src = ei;
  const int* dst = ei + E;

  char* ws = (char*)d_ws;
  size_t off = 0;
  auto alloc = [&](size_t bytes) -> void* {
    void* p = ws + off;
    off += (bytes + 255) & ~(size_t)255;
    return p;
  };
  unsigned short* bufA = (unsigned short*)alloc((size_t)N * 128 * 2);
  unsigned short* bufB = (unsigned short*)alloc((size_t)N * 128 * 2);
  float* dinv    = (float*)alloc((size_t)N * 4);
  int*   rowptr  = (int*)alloc((size_t)(N + 1) * 4);
  int2*  csr     = (int2*)alloc((size_t)E * 8);
  short* Wp1     = (short*)alloc((size_t)2 * 8 * 4 * 64 * 8 * 2);
  short* Wp2     = (short*)alloc((size_t)2 * 8 * 4 * 64 * 8 * 2);
  int*   tmp     = (int*)alloc((size_t)N * 4);
  int*   deg     = (int*)alloc((size_t)N * 4);   // zeroed region starts here
  int*   cnt     = (int*)alloc((size_t)N * 4);
  int*   bsums   = (int*)alloc(1024);
  size_t zbytes = ((char*)bsums + 1024) - (char*)deg;
  hipMemsetAsync(deg, 0, zbytes, stream);

  const int E4B = (E + 1023) / 1024;
  const int NB = (N + 255) / 256;
  const int SB = (N + 511) / 512;

  // W packing (independent of graph prep)
  wpack_kernel<<<8, 256, 0, stream>>>(W1, Wp1);
  wpack_kernel<<<8, 256, 0, stream>>>(W2, Wp2);

  deg_kernel<<<E4B, 256, 0, stream>>>(dst, deg, E);
  scan1_kernel<<<SB, 512, 0, stream>>>(deg, tmp, bsums, N);
  scan2_kernel<<<1, 256, 0, stream>>>(bsums, SB);
  scan3_kernel<<<NB, 256, 0, stream>>>(tmp, bsums, deg, rowptr, dinv, N);
  scatter_kernel<<<E4B, 256, 0, stream>>>(src, dst, rowptr, cnt, csr, E);

  const int G16 = (N + 15) / 16;
  const int AB = (N + 15) / 16;
  const int DB = (N + 15) / 16;

  // layer 1 GEMM (M=16-tile form): bufA = dinv*(x@W1)
  gemm1_kernel<<<G16, 256, 0, stream>>>(x, Wp1, dinv, bufA, N);
  // FUSED: agg layer1 (+b1, relu) -> z1 in LDS -> MFMA z1@W2:
  //   bufB = dinv*(z1@W2)   (z1 never touches global memory)
  agg_gemm_kernel<<<AB, 256, 0, stream>>>(bufA, dinv, rowptr, csr, b1, Wp2,
                                          bufB, N);
  // layer 2 aggregation: bufA = z2 = dinv*(sum)+self + b2
  agg_kernel<<<AB, 256, 0, stream>>>(bufB, dinv, rowptr, csr, b2, bufA, 0, N);
  // decode over dst-CSR
  decode_kernel<<<DB, 256, 0, stream>>>(bufA, rowptr, csr, (float*)d_out, N);
}

// Round 10
// 292.816 us; speedup vs baseline: 1.2350x; 1.0387x over previous
//
#include <hip/hip_runtime.h>

// GCN link predictor: z1 = relu(GCNConv(x,W1,b1)); z2 = GCNConv(z1,W2,b2);
// out[e] = dot(z2[src[e]], z2[dst[e]])
// R9-R17: 64-row gemm forms latency-bound 50-130us; compiler always sinks
//   const __restrict__ global W/prefetch loads (5 failed residency attempts).
// R18 WIN (333->313.5): fused gemm2 into agg1 via 4KB LDS z1 tile.
// R19 WIN (313.5->304.2): gemm1 rewritten as M=16-tile/block, grid 6250,
//   straight-line, occ 70%. Remaining limiter: strided per-wave A loads
//   (16 cache lines per load instr, 4x wave redundancy) feeding a serial
//   convert->MFMA chain.
// R20: cooperative LDS A-staging: 256 threads load the 16x512B fp32 tile
//   fully coalesced, convert to bf16, ds_write_b128 into 4KB LDS with
//   slot^(row&7) swizzle (conflict-free read). B-frag loads issued BEFORE
//   __syncthreads -- barrier pins them (compiler can't sink across it),
//   overlapping W-L2 latency with staging. ds_read frags (~120cyc) replace
//   L3-latency strided loads.

typedef __attribute__((ext_vector_type(8))) short short8;  // 8 bf16 = 4 VGPRs
typedef __attribute__((ext_vector_type(4))) float f32x4;

__device__ __forceinline__ unsigned bf16_rne(float x) {
  unsigned u = __builtin_bit_cast(unsigned, x);
  return (u + 0x7FFFu + ((u >> 16) & 1u)) >> 16;
}
__device__ __forceinline__ float bf2f(unsigned short u) {
  return __builtin_bit_cast(float, ((unsigned)u) << 16);
}

// ---------- degree: 4 edges/thread ----------
__global__ __launch_bounds__(256) void deg_kernel(const int* __restrict__ dst,
                                                  int* __restrict__ deg, int E) {
  int base = blockIdx.x * 1024 + threadIdx.x;
#pragma unroll
  for (int i = 0; i < 4; ++i) {
    int e = base + i * 256;
    if (e < E) atomicAdd(&deg[dst[e]], 1);
  }
}

// ---------- block scan (512 elems/block) ----------
__global__ __launch_bounds__(512) void scan1_kernel(const int* __restrict__ in,
                                                    int* __restrict__ tmp,
                                                    int* __restrict__ bsums, int n) {
  __shared__ int sm[2][512];
  int t = threadIdx.x;
  int gid = blockIdx.x * 512 + t;
  int v = (gid < n) ? in[gid] : 0;
  int pp = 0;
  sm[0][t] = v;
  __syncthreads();
  for (int off = 1; off < 512; off <<= 1) {
    int nv = sm[pp][t];
    if (t >= off) nv += sm[pp][t - off];
    sm[pp ^ 1][t] = nv;
    pp ^= 1;
    __syncthreads();
  }
  int inc = sm[pp][t];
  if (gid < n) tmp[gid] = inc;
  if (t == 511) bsums[blockIdx.x] = inc;
}

__global__ __launch_bounds__(256) void scan2_kernel(int* bsums, int nb) {
  __shared__ int sm[2][256];
  int t = threadIdx.x;
  int v = (t < nb) ? bsums[t] : 0;
  int pp = 0;
  sm[0][t] = v;
  __syncthreads();
  for (int off = 1; off < 256; off <<= 1) {
    int nv = sm[pp][t];
    if (t >= off) nv += sm[pp][t - off];
    sm[pp ^ 1][t] = nv;
    pp ^= 1;
    __syncthreads();
  }
  int inc = sm[pp][t];
  if (t < nb) bsums[t] = inc - v;  // exclusive
}

// rowptr from scan, plus dinv = rsqrt(deg+1) fused here
__global__ __launch_bounds__(256) void scan3_kernel(const int* __restrict__ tmp,
                                                    const int* __restrict__ bsums,
                                                    const int* __restrict__ deg,
                                                    int* __restrict__ rowptr,
                                                    float* __restrict__ dinv, int n) {
  int gid = blockIdx.x * 256 + threadIdx.x;
  if (gid < n) {
    rowptr[gid + 1] = tmp[gid] + bsums[gid >> 9];
    dinv[gid] = rsqrtf((float)(deg[gid] + 1));  // +1 self loop
  }
  if (gid == 0) rowptr[0] = 0;
}

// CSR scatter: one int2 {src, eid} store per edge; 4 edges/thread for MLP.
__global__ __launch_bounds__(256) void scatter_kernel(const int* __restrict__ src,
                                                      const int* __restrict__ dst,
                                                      const int* __restrict__ rowptr,
                                                      int* __restrict__ cnt,
                                                      int2* __restrict__ csr, int E) {
  int base = blockIdx.x * 1024 + threadIdx.x;
#pragma unroll
  for (int i = 0; i < 4; ++i) {
    int e = base + i * 256;
    if (e < E) {
      int d = dst[e];
      int pos = rowptr[d] + atomicAdd(&cnt[d], 1);
      csr[pos] = make_int2(src[e], e);
    }
  }
}

// ---------- pack W[128][128] fp32 -> bf16 hi/lo in MFMA B-fragment order ----
// B frag (16x16x32): lane holds B[k=(lane>>4)*8+j][n=lane&15], j=0..7.
// Layout: Wp[half(0=hi,1=lo)][ct(8)][kf(4)][lane(64)][8] bf16.
__global__ __launch_bounds__(256) void wpack_kernel(const float* __restrict__ W,
                                                    short* __restrict__ Wp) {
  int t = blockIdx.x * 256 + threadIdx.x;  // 2048 = ct*256 + kf*64 + lane
  if (t >= 2048) return;
  int lane = t & 63;
  int kf = (t >> 6) & 3;
  int ct = t >> 8;
  int col = ct * 16 + (lane & 15);
  int k0 = kf * 32 + (lane >> 4) * 8;
  short* dh = Wp + ((((0 * 8 + ct) * 4 + kf) * 64) + lane) * 8;
  short* dl = Wp + ((((1 * 8 + ct) * 4 + kf) * 64) + lane) * 8;
  for (int j = 0; j < 8; ++j) {
    float w = W[(k0 + j) * 128 + col];
    unsigned h = bf16_rne(w);
    float hf = __builtin_bit_cast(float, h << 16);
    unsigned lo = bf16_rne(w - hf);
    dh[j] = (short)h;
    dl[j] = (short)lo;
  }
}

// ---------- layer-1 GEMM, M=16-tile + LDS A-staging ----------
// Grid ceil(M/16). Stage: thread(row=tid>>4, seg=tid&15) loads 32B fp32
// coalesced, converts to 16B bf16, ds_write at slot seg^(row&7) (swizzle).
// B-frag loads issued BEFORE the barrier (pinned early by the barrier).
// After barrier: ds_read_b128 A-frags, 16 MFMAs, scale dinv, store.
__global__ __launch_bounds__(256, 4) void gemm1_kernel(const float* __restrict__ A,
                                                       const short* __restrict__ Wp,
                                                       const float* __restrict__ dinv,
                                                       unsigned short* __restrict__ out,
                                                       int M) {
  __shared__ short8 lds_a[256];  // 4 KB: [row16][slot16], slot ^= row&7

  const int tid = threadIdx.x;
  const int wave = tid >> 6;
  const int lane = tid & 63;
  const int quad = lane >> 4;
  const int l15 = lane & 15;
  const int ct0 = wave * 2;
  const int ct1 = wave * 2 + 1;
  const int colbase = wave * 32 + l15;
  const int rb0 = blockIdx.x * 16;
  const bool full = (rb0 + 16 <= M);
  const short8* Wp8 = (const short8*)Wp;

  // ---- stage A: coalesced fp32 load -> bf16 -> swizzled LDS ----
  {
    const int row = tid >> 4;
    const int seg = tid & 15;
    float4 a0 = {0.f, 0.f, 0.f, 0.f}, a1 = {0.f, 0.f, 0.f, 0.f};
    if (full || rb0 + row < M) {
      const float4* p = (const float4*)A + (size_t)(rb0 + row) * 32 + seg * 2;
      a0 = p[0];
      a1 = p[1];
    }
    const float av[8] = {a0.x, a0.y, a0.z, a0.w, a1.x, a1.y, a1.z, a1.w};
    short8 w;
#pragma unroll
    for (int j = 0; j < 8; ++j) w[j] = (short)bf16_rne(av[j]);
    lds_a[row * 16 + (seg ^ (row & 7))] = w;
  }

  // ---- B fragments: issued BEFORE the barrier so they overlap staging ----
  short8 bh0[4], bh1[4], bl0[4], bl1[4];
#pragma unroll
  for (int f = 0; f < 4; ++f) {
    bh0[f] = Wp8[((0 * 8 + ct0) * 4 + f) * 64 + lane];
    bh1[f] = Wp8[((0 * 8 + ct1) * 4 + f) * 64 + lane];
    bl0[f] = Wp8[((1 * 8 + ct0) * 4 + f) * 64 + lane];
    bl1[f] = Wp8[((1 * 8 + ct1) * 4 + f) * 64 + lane];
  }

  __syncthreads();

  // ---- A fragments from LDS: af[f][j] = A[l15][f*32+quad*8+j] ----
  short8 af[4];
#pragma unroll
  for (int f = 0; f < 4; ++f) af[f] = lds_a[l15 * 16 + ((f * 4 + quad) ^ (l15 & 7))];

  f32x4 a0h = {0.f, 0.f, 0.f, 0.f};
  f32x4 a0l = {0.f, 0.f, 0.f, 0.f};
  f32x4 a1h = {0.f, 0.f, 0.f, 0.f};
  f32x4 a1l = {0.f, 0.f, 0.f, 0.f};
#pragma unroll
  for (int f = 0; f < 4; ++f) {
    a0h = __builtin_amdgcn_mfma_f32_16x16x32_bf16(af[f], bh0[f], a0h, 0, 0, 0);
    a1h = __builtin_amdgcn_mfma_f32_16x16x32_bf16(af[f], bh1[f], a1h, 0, 0, 0);
    a0l = __builtin_amdgcn_mfma_f32_16x16x32_bf16(af[f], bl0[f], a0l, 0, 0, 0);
    a1l = __builtin_amdgcn_mfma_f32_16x16x32_bf16(af[f], bl1[f], a1l, 0, 0, 0);
  }

  // ---- epilogue: C/D layout col=lane&15, row=quad*4+i ----
  if (full) {
    const f32x4 dv = *(const f32x4*)(dinv + rb0 + quad * 4);
#pragma unroll
    for (int i = 0; i < 4; ++i) {
      const int r = rb0 + quad * 4 + i;
      out[(size_t)r * 128 + colbase] =
          (unsigned short)bf16_rne((a0h[i] + a0l[i]) * dv[i]);
      out[(size_t)r * 128 + colbase + 16] =
          (unsigned short)bf16_rne((a1h[i] + a1l[i]) * dv[i]);
    }
  } else {
#pragma unroll
    for (int i = 0; i < 4; ++i) {
      const int r = rb0 + quad * 4 + i;
      if (r < M) {
        const float d = dinv[r];
        out[(size_t)r * 128 + colbase] =
            (unsigned short)bf16_rne((a0h[i] + a0l[i]) * d);
        out[(size_t)r * 128 + colbase + 16] =
            (unsigned short)bf16_rne((a1h[i] + a1l[i]) * d);
      }
    }
  }
}

// ---------- FUSED agg1 + gemm2 ----------
// Phase 1 (per node, 16 lanes): z1 = relu(dinv*(xw_self + sum_nbr xw) + b1),
//   bf16 rows into 4KB LDS tile (chunk index XOR row -> conflict-free reads).
// Phase 2 (per wave): 16x128 z1-tile @ 128x128 W2 via MFMA, wave = 2
//   col-tiles x hi/lo; out = bf16(dinv[r] * (z1@W2)[r,:]).
__global__ __launch_bounds__(256) void agg_gemm_kernel(
    const unsigned short* __restrict__ xw, const float* __restrict__ dinv,
    const int* __restrict__ rowptr, const int2* __restrict__ csr,
    const float* __restrict__ bias, const short* __restrict__ Wp,
    unsigned short* __restrict__ out, int N) {
  __shared__ short8 z1t[16][16];  // [row][chunk ^ row], 4 KB

  const int tid = threadIdx.x;
  const int node0 = blockIdx.x * 16;
  const int n = tid >> 4;  // local node 0..15
  const int l = tid & 15;  // chunk lane 0..15
  const int node = node0 + n;

  // ---- phase 1: aggregation (no early return: barrier below) ----
  short8 o = {0, 0, 0, 0, 0, 0, 0, 0};
  if (node < N) {
    const short8* xw8 = (const short8*)xw;
    short8 sv = xw8[(size_t)node * 16 + l];
    float acc[8];
#pragma unroll
    for (int j = 0; j < 8; ++j) acc[j] = bf2f((unsigned short)sv[j]);
    int s = rowptr[node], e = rowptr[node + 1];
    int k = s;
    for (; k + 4 <= e; k += 4) {
      int j0 = csr[k].x, j1 = csr[k + 1].x, j2 = csr[k + 2].x, j3 = csr[k + 3].x;
      short8 v0 = xw8[(size_t)j0 * 16 + l];
      short8 v1 = xw8[(size_t)j1 * 16 + l];
      short8 v2 = xw8[(size_t)j2 * 16 + l];
      short8 v3 = xw8[(size_t)j3 * 16 + l];
#pragma unroll
      for (int j = 0; j < 8; ++j) {
        acc[j] += (bf2f((unsigned short)v0[j]) + bf2f((unsigned short)v1[j])) +
                  (bf2f((unsigned short)v2[j]) + bf2f((unsigned short)v3[j]));
      }
    }
    for (; k < e; ++k) {
      short8 v = xw8[(size_t)csr[k].x * 16 + l];
#pragma unroll
      for (int j = 0; j < 8; ++j) acc[j] += bf2f((unsigned short)v[j]);
    }
    float di = dinv[node];
    const float4* b4 = (const float4*)bias;
    float4 bb0 = b4[l * 2], bb1 = b4[l * 2 + 1];
    float bv[8] = {bb0.x, bb0.y, bb0.z, bb0.w, bb1.x, bb1.y, bb1.z, bb1.w};
#pragma unroll
    for (int j = 0; j < 8; ++j) {
      float v = fmaf(di, acc[j], bv[j]);
      v = fmaxf(v, 0.f);  // relu (layer 1)
      o[j] = (short)bf16_rne(v);
    }
  }
  z1t[n][l ^ n] = o;  // swizzled store
  __syncthreads();

  // ---- phase 2: MFMA 16x128 @ 128x128 ----
  const int wave = tid >> 6;
  const int lane = tid & 63;
  const int quad = lane >> 4;
  const int l15 = lane & 15;
  const int ct0 = wave * 2;
  const int ct1 = wave * 2 + 1;

  short8 af[4];  // A frag: lane holds z1[m=l15][k=f*32+quad*8 .. +7]
#pragma unroll
  for (int f = 0; f < 4; ++f) af[f] = z1t[l15][(f * 4 + quad) ^ l15];

  const short8* Wp8 = (const short8*)Wp;
  f32x4 a0h = {0.f, 0.f, 0.f, 0.f};
  f32x4 a0l = {0.f, 0.f, 0.f, 0.f};
  f32x4 a1h = {0.f, 0.f, 0.f, 0.f};
  f32x4 a1l = {0.f, 0.f, 0.f, 0.f};
#pragma unroll
  for (int f = 0; f < 4; ++f) {
    const short8 bh0 = Wp8[((0 * 8 + ct0) * 4 + f) * 64 + lane];
    const short8 bh1 = Wp8[((0 * 8 + ct1) * 4 + f) * 64 + lane];
    const short8 bl0 = Wp8[((1 * 8 + ct0) * 4 + f) * 64 + lane];
    const short8 bl1 = Wp8[((1 * 8 + ct1) * 4 + f) * 64 + lane];
    a0h = __builtin_amdgcn_mfma_f32_16x16x32_bf16(af[f], bh0, a0h, 0, 0, 0);
    a1h = __builtin_amdgcn_mfma_f32_16x16x32_bf16(af[f], bh1, a1h, 0, 0, 0);
    a0l = __builtin_amdgcn_mfma_f32_16x16x32_bf16(af[f], bl0, a0l, 0, 0, 0);
    a1l = __builtin_amdgcn_mfma_f32_16x16x32_bf16(af[f], bl1, a1l, 0, 0, 0);
  }

  // epilogue: C/D layout col=lane&15, row=quad*4+i; out = dinv[r]*(z1@W2)
  if (node0 + 16 <= N) {
    const f32x4 dv = *(const f32x4*)(dinv + node0 + quad * 4);
#pragma unroll
    for (int i = 0; i < 4; ++i) {
      const int r = node0 + quad * 4 + i;
      out[(size_t)r * 128 + ct0 * 16 + l15] =
          (unsigned short)bf16_rne((a0h[i] + a0l[i]) * dv[i]);
      out[(size_t)r * 128 + ct1 * 16 + l15] =
          (unsigned short)bf16_rne((a1h[i] + a1l[i]) * dv[i]);
    }
  } else {
#pragma unroll
    for (int i = 0; i < 4; ++i) {
      const int r = node0 + quad * 4 + i;
      if (r < N) {
        const float d = dinv[r];
        out[(size_t)r * 128 + ct0 * 16 + l15] =
            (unsigned short)bf16_rne((a0h[i] + a0l[i]) * d);
        out[(size_t)r * 128 + ct1 * 16 + l15] =
            (unsigned short)bf16_rne((a1h[i] + a1l[i]) * d);
      }
    }
  }
}

// ---------- aggregation over prescaled bf16 rows (layer 2) ----------
__global__ __launch_bounds__(256) void agg_kernel(const unsigned short* __restrict__ xw,
                                                  const float* __restrict__ dinv,
                                                  const int* __restrict__ rowptr,
                                                  const int2* __restrict__ csr,
                                                  const float* __restrict__ bias,
                                                  unsigned short* __restrict__ out,
                                                  int relu, int N) {
  int node = blockIdx.x * 16 + (threadIdx.x >> 4);
  int l = threadIdx.x & 15;
  if (node >= N) return;
  const short8* xw8 = (const short8*)xw;  // row = 16 short8 groups
  short8 sv = xw8[(size_t)node * 16 + l];
  float acc[8];
#pragma unroll
  for (int j = 0; j < 8; ++j) acc[j] = bf2f((unsigned short)sv[j]);
  int s = rowptr[node], e = rowptr[node + 1];
  int k = s;
  for (; k + 4 <= e; k += 4) {
    int j0 = csr[k].x, j1 = csr[k + 1].x, j2 = csr[k + 2].x, j3 = csr[k + 3].x;
    short8 v0 = xw8[(size_t)j0 * 16 + l];
    short8 v1 = xw8[(size_t)j1 * 16 + l];
    short8 v2 = xw8[(size_t)j2 * 16 + l];
    short8 v3 = xw8[(size_t)j3 * 16 + l];
#pragma unroll
    for (int j = 0; j < 8; ++j) {
      acc[j] += (bf2f((unsigned short)v0[j]) + bf2f((unsigned short)v1[j])) +
                (bf2f((unsigned short)v2[j]) + bf2f((unsigned short)v3[j]));
    }
  }
  for (; k < e; ++k) {
    short8 v = xw8[(size_t)csr[k].x * 16 + l];
#pragma unroll
    for (int j = 0; j < 8; ++j) acc[j] += bf2f((unsigned short)v[j]);
  }
  float di = dinv[node];
  const float4* b4 = (const float4*)bias;
  float4 bb0 = b4[l * 2], bb1 = b4[l * 2 + 1];
  float bv[8] = {bb0.x, bb0.y, bb0.z, bb0.w, bb1.x, bb1.y, bb1.z, bb1.w};
  short8 o;
#pragma unroll
  for (int j = 0; j < 8; ++j) {
    float v = fmaf(di, acc[j], bv[j]);
    if (relu) v = fmaxf(v, 0.f);
    o[j] = (short)bf16_rne(v);
  }
  ((short8*)out)[(size_t)node * 16 + l] = o;
}

// ---------- decode over dst-CSR, bf16 z2: 16 lanes/node ----------
__global__ __launch_bounds__(256) void decode_kernel(const unsigned short* __restrict__ z,
                                                     const int* __restrict__ rowptr,
                                                     const int2* __restrict__ csr,
                                                     float* __restrict__ out, int N) {
  int node = blockIdx.x * 16 + (threadIdx.x >> 4);
  int l = threadIdx.x & 15;
  if (node >= N) return;
  const short8* z8 = (const short8*)z;
  short8 zv = z8[(size_t)node * 16 + l];
  float zd[8];
#pragma unroll
  for (int j = 0; j < 8; ++j) zd[j] = bf2f((unsigned short)zv[j]);
  int s = rowptr[node], e = rowptr[node + 1];
  int k = s;
  for (; k + 4 <= e; k += 4) {
    int2 c0 = csr[k], c1 = csr[k + 1], c2 = csr[k + 2], c3 = csr[k + 3];
    short8 v0 = z8[(size_t)c0.x * 16 + l];
    short8 v1 = z8[(size_t)c1.x * 16 + l];
    short8 v2 = z8[(size_t)c2.x * 16 + l];
    short8 v3 = z8[(size_t)c3.x * 16 + l];
    float p0 = 0.f, p1 = 0.f, p2 = 0.f, p3 = 0.f;
#pragma unroll
    for (int j = 0; j < 8; ++j) {
      p0 = fmaf(zd[j], bf2f((unsigned short)v0[j]), p0);
      p1 = fmaf(zd[j], bf2f((unsigned short)v1[j]), p1);
      p2 = fmaf(zd[j], bf2f((unsigned short)v2[j]), p2);
      p3 = fmaf(zd[j], bf2f((unsigned short)v3[j]), p3);
    }
#pragma unroll
    for (int off = 8; off > 0; off >>= 1) {
      p0 += __shfl_xor(p0, off);
      p1 += __shfl_xor(p1, off);
      p2 += __shfl_xor(p2, off);
      p3 += __shfl_xor(p3, off);
    }
    if (l == 0) {
      out[c0.y] = p0;
      out[c1.y] = p1;
      out[c2.y] = p2;
      out[c3.y] = p3;
    }
  }
  for (; k < e; ++k) {
    int2 c = csr[k];
    short8 v = z8[(size_t)c.x * 16 + l];
    float p = 0.f;
#pragma unroll
    for (int j = 0; j < 8; ++j) p = fmaf(zd[j], bf2f((unsigned short)v[j]), p);
#pragma unroll
    for (int off = 8; off > 0; off >>= 1) p += __shfl_xor(p, off);
    if (l == 0) out[c.y] = p;
  }
}

extern "C" void kernel_launch(void* const* d_in, const int* in_sizes, int n_in,
                              void* d_out, int out_size, void* d_ws, size_t ws_size,
                              hipStream_t stream) {
  const float* x  = (const float*)d_in[0];
  const int*   ei = (const int*)d_in[1];
  const float* W1 = (const float*)d_in[2];
  const float* b1 = (const float*)d_in[3];
  const float* W2 = (const float*)d_in[4];
  const float* b2 = (const float*)d_in[5];

  const int N = in_sizes[0] / 128;
  const int E = in_sizes[1] / 2;
  const int* src = ei;
  const int* dst = ei + E;

  char* ws = (char*)d_ws;
  size_t off = 0;
  auto alloc = [&](size_t bytes) -> void* {
    void* p = ws + off;
    off += (bytes + 255) & ~(size_t)255;
    return p;
  };
  unsigned short* bufA = (unsigned short*)alloc((size_t)N * 128 * 2);
  unsigned short* bufB = (unsigned short*)alloc((size_t)N * 128 * 2);
  float* dinv    = (float*)alloc((size_t)N * 4);
  int*   rowptr  = (int*)alloc((size_t)(N + 1) * 4);
  int2*  csr     = (int2*)alloc((size_t)E * 8);
  short* Wp1     = (short*)alloc((size_t)2 * 8 * 4 * 64 * 8 * 2);
  short* Wp2     = (short*)alloc((size_t)2 * 8 * 4 * 64 * 8 * 2);
  int*   tmp     = (int*)alloc((size_t)N * 4);
  int*   deg     = (int*)alloc((size_t)N * 4);   // zeroed region starts here
  int*   cnt     = (int*)alloc((size_t)N * 4);
  int*   bsums   = (int*)alloc(1024);
  size_t zbytes = ((char*)bsums + 1024) - (char*)deg;
  hipMemsetAsync(deg, 0, zbytes, stream);

  const int E4B = (E + 1023) / 1024;
  const int NB = (N + 255) / 256;
  const int SB = (N + 511) / 512;

  // W packing (independent of graph prep)
  wpack_kernel<<<8, 256, 0, stream>>>(W1, Wp1);
  wpack_kernel<<<8, 256, 0, stream>>>(W2, Wp2);

  deg_kernel<<<E4B, 256, 0, stream>>>(dst, deg, E);
  scan1_kernel<<<SB, 512, 0, stream>>>(deg, tmp, bsums, N);
  scan2_kernel<<<1, 256, 0, stream>>>(bsums, SB);
  scan3_kernel<<<NB, 256, 0, stream>>>(tmp, bsums, deg, rowptr, dinv, N);
  scatter_kernel<<<E4B, 256, 0, stream>>>(src, dst, rowptr, cnt, csr, E);

  const int G16 = (N + 15) / 16;
  const int AB = (N + 15) / 16;
  const int DB = (N + 15) / 16;

  // layer 1 GEMM (M=16-tile, LDS A-staging): bufA = dinv*(x@W1)
  gemm1_kernel<<<G16, 256, 0, stream>>>(x, Wp1, dinv, bufA, N);
  // FUSED: agg layer1 (+b1, relu) -> z1 in LDS -> MFMA z1@W2:
  //   bufB = dinv*(z1@W2)   (z1 never touches global memory)
  agg_gemm_kernel<<<AB, 256, 0, stream>>>(bufA, dinv, rowptr, csr, b1, Wp2,
                                          bufB, N);
  // layer 2 aggregation: bufA = z2 = dinv*(sum)+self + b2
  agg_kernel<<<AB, 256, 0, stream>>>(bufB, dinv, rowptr, csr, b2, bufA, 0, N);
  // decode over dst-CSR
  decode_kernel<<<DB, 256, 0, stream>>>(bufA, rowptr, csr, (float*)d_out, N);
}

// Round 11
// 282.593 us; speedup vs baseline: 1.2797x; 1.0362x over previous
//
#include <hip/hip_runtime.h>

// GCN link predictor: z1 = relu(GCNConv(x,W1,b1)); z2 = GCNConv(z1,W2,b2);
// out[e] = dot(z2[src[e]], z2[dst[e]])
// R18 WIN (333->313.5): fused gemm2 into agg1 via 4KB LDS z1 tile.
// R19 WIN (313.5->304.2): gemm1 as M=16-tile/block, grid 6250, occ 70%.
// R20 WIN (304.2->292.8): gemm1 LDS A-staging (coalesced fp32 load -> bf16 ->
//   swizzled 4KB LDS; B loads pinned before barrier). gemm1 out of top-5;
//   agg_gemm now leads at ~44us, 2.45TB/s — gather plane near its floor.
// R21: attack the SERIAL DISPATCH SCHEDULE, not kernel internals:
//   - prep_kernel: wpack x2 + deg packed into one launch (was 3).
//   - scan23: scan2 (1-block dispatch!) folded into scan3 (each block
//     redundantly scans <=196 bsums in LDS).
//   - scatgemm: scatter (586 sparse-atomic blocks) + gemm1 (6250 streaming
//     blocks) in ONE launch -> scatter hides under gemm1.
//   - agg/decode at 128 thr (8 nodes/block) for degree-variance tail packing.

typedef __attribute__((ext_vector_type(8))) short short8;  // 8 bf16 = 4 VGPRs
typedef __attribute__((ext_vector_type(4))) float f32x4;

__device__ __forceinline__ unsigned bf16_rne(float x) {
  unsigned u = __builtin_bit_cast(unsigned, x);
  return (u + 0x7FFFu + ((u >> 16) & 1u)) >> 16;
}
__device__ __forceinline__ float bf2f(unsigned short u) {
  return __builtin_bit_cast(float, ((unsigned)u) << 16);
}

// ---------- wpack body: W[128][128] fp32 -> bf16 hi/lo, MFMA B-frag order --
// B frag (16x16x32): lane holds B[k=(lane>>4)*8+j][n=lane&15], j=0..7.
// Layout: Wp[half(0=hi,1=lo)][ct(8)][kf(4)][lane(64)][8] bf16.
__device__ __forceinline__ void wpack_body(const float* __restrict__ W,
                                           short* __restrict__ Wp, int t) {
  int lane = t & 63;
  int kf = (t >> 6) & 3;
  int ct = t >> 8;
  int col = ct * 16 + (lane & 15);
  int k0 = kf * 32 + (lane >> 4) * 8;
  short* dh = Wp + ((((0 * 8 + ct) * 4 + kf) * 64) + lane) * 8;
  short* dl = Wp + ((((1 * 8 + ct) * 4 + kf) * 64) + lane) * 8;
  for (int j = 0; j < 8; ++j) {
    float w = W[(k0 + j) * 128 + col];
    unsigned h = bf16_rne(w);
    float hf = __builtin_bit_cast(float, h << 16);
    unsigned lo = bf16_rne(w - hf);
    dh[j] = (short)h;
    dl[j] = (short)lo;
  }
}

// ---------- prep: wpack(W1) | wpack(W2) | deg, block-range partitioned -----
__global__ __launch_bounds__(256) void prep_kernel(const float* __restrict__ W1,
                                                   short* __restrict__ Wp1,
                                                   const float* __restrict__ W2,
                                                   short* __restrict__ Wp2,
                                                   const int* __restrict__ dst,
                                                   int* __restrict__ deg, int E) {
  const int b = blockIdx.x;
  if (b < 8) {
    wpack_body(W1, Wp1, b * 256 + threadIdx.x);
  } else if (b < 16) {
    wpack_body(W2, Wp2, (b - 8) * 256 + threadIdx.x);
  } else {
    int base = (b - 16) * 1024 + threadIdx.x;
#pragma unroll
    for (int i = 0; i < 4; ++i) {
      int e = base + i * 256;
      if (e < E) atomicAdd(&deg[dst[e]], 1);
    }
  }
}

// ---------- block scan (512 elems/block) ----------
__global__ __launch_bounds__(512) void scan1_kernel(const int* __restrict__ in,
                                                    int* __restrict__ tmp,
                                                    int* __restrict__ bsums, int n) {
  __shared__ int sm[2][512];
  int t = threadIdx.x;
  int gid = blockIdx.x * 512 + t;
  int v = (gid < n) ? in[gid] : 0;
  int pp = 0;
  sm[0][t] = v;
  __syncthreads();
  for (int off = 1; off < 512; off <<= 1) {
    int nv = sm[pp][t];
    if (t >= off) nv += sm[pp][t - off];
    sm[pp ^ 1][t] = nv;
    pp ^= 1;
    __syncthreads();
  }
  int inc = sm[pp][t];
  if (gid < n) tmp[gid] = inc;
  if (t == 511) bsums[blockIdx.x] = inc;
}

// ---------- scan2+scan3 merged: each block scans bsums in LDS, then
// rowptr[gid+1] = tmp[gid] + excl_bsums[gid>>9]; dinv fused. nb <= 256. ----
__global__ __launch_bounds__(256) void scan23_kernel(const int* __restrict__ tmp,
                                                     const int* __restrict__ bsums,
                                                     const int* __restrict__ deg,
                                                     int* __restrict__ rowptr,
                                                     float* __restrict__ dinv,
                                                     int n, int nb) {
  __shared__ int sm[2][256];
  __shared__ int orig[256];
  int t = threadIdx.x;
  int v = (t < nb) ? bsums[t] : 0;
  orig[t] = v;
  int pp = 0;
  sm[0][t] = v;
  __syncthreads();
  for (int off = 1; off < 256; off <<= 1) {
    int nv = sm[pp][t];
    if (t >= off) nv += sm[pp][t - off];
    sm[pp ^ 1][t] = nv;
    pp ^= 1;
    __syncthreads();
  }
  int gid = blockIdx.x * 256 + t;
  if (gid < n) {
    int b = gid >> 9;
    rowptr[gid + 1] = tmp[gid] + (sm[pp][b] - orig[b]);  // exclusive offset
    dinv[gid] = rsqrtf((float)(deg[gid] + 1));           // +1 self loop
  }
  if (gid == 0) rowptr[0] = 0;
}

// ---------- scatter | gemm1 fused dispatch ----------
// Blocks [0, SCB): CSR scatter (one int2 {src,eid} per edge, 4 edges/thread).
// Blocks [SCB, SCB+G16): layer-1 GEMM, M=16-tile + LDS A-staging (R20 form).
// Independent work -> scatter's sparse atomics hide under gemm1 streaming.
__global__ __launch_bounds__(256, 4) void scatgemm_kernel(
    const int* __restrict__ src, const int* __restrict__ dst,
    const int* __restrict__ rowptr, int* __restrict__ cnt,
    int2* __restrict__ csr, int E, int SCB, const float* __restrict__ A,
    const short* __restrict__ Wp, const float* __restrict__ dinv,
    unsigned short* __restrict__ out, int M) {
  __shared__ short8 lds_a[256];  // 4 KB (gemm path only)

  if ((int)blockIdx.x < SCB) {
    // ---- scatter path ----
    int base = blockIdx.x * 1024 + threadIdx.x;
#pragma unroll
    for (int i = 0; i < 4; ++i) {
      int e = base + i * 256;
      if (e < E) {
        int d = dst[e];
        int pos = rowptr[d] + atomicAdd(&cnt[d], 1);
        csr[pos] = make_int2(src[e], e);
      }
    }
    return;
  }

  // ---- gemm1 path (R20: coalesced stage -> swizzled LDS -> MFMA) ----
  const int bid = blockIdx.x - SCB;
  const int tid = threadIdx.x;
  const int wave = tid >> 6;
  const int lane = tid & 63;
  const int quad = lane >> 4;
  const int l15 = lane & 15;
  const int ct0 = wave * 2;
  const int ct1 = wave * 2 + 1;
  const int colbase = wave * 32 + l15;
  const int rb0 = bid * 16;
  const bool full = (rb0 + 16 <= M);
  const short8* Wp8 = (const short8*)Wp;

  {
    const int row = tid >> 4;
    const int seg = tid & 15;
    float4 a0 = {0.f, 0.f, 0.f, 0.f}, a1 = {0.f, 0.f, 0.f, 0.f};
    if (full || rb0 + row < M) {
      const float4* p = (const float4*)A + (size_t)(rb0 + row) * 32 + seg * 2;
      a0 = p[0];
      a1 = p[1];
    }
    const float av[8] = {a0.x, a0.y, a0.z, a0.w, a1.x, a1.y, a1.z, a1.w};
    short8 w;
#pragma unroll
    for (int j = 0; j < 8; ++j) w[j] = (short)bf16_rne(av[j]);
    lds_a[row * 16 + (seg ^ (row & 7))] = w;
  }

  // B frags issued BEFORE the barrier (barrier pins them; overlap staging)
  short8 bh0[4], bh1[4], bl0[4], bl1[4];
#pragma unroll
  for (int f = 0; f < 4; ++f) {
    bh0[f] = Wp8[((0 * 8 + ct0) * 4 + f) * 64 + lane];
    bh1[f] = Wp8[((0 * 8 + ct1) * 4 + f) * 64 + lane];
    bl0[f] = Wp8[((1 * 8 + ct0) * 4 + f) * 64 + lane];
    bl1[f] = Wp8[((1 * 8 + ct1) * 4 + f) * 64 + lane];
  }

  __syncthreads();

  short8 af[4];
#pragma unroll
  for (int f = 0; f < 4; ++f) af[f] = lds_a[l15 * 16 + ((f * 4 + quad) ^ (l15 & 7))];

  f32x4 a0h = {0.f, 0.f, 0.f, 0.f};
  f32x4 a0l = {0.f, 0.f, 0.f, 0.f};
  f32x4 a1h = {0.f, 0.f, 0.f, 0.f};
  f32x4 a1l = {0.f, 0.f, 0.f, 0.f};
#pragma unroll
  for (int f = 0; f < 4; ++f) {
    a0h = __builtin_amdgcn_mfma_f32_16x16x32_bf16(af[f], bh0[f], a0h, 0, 0, 0);
    a1h = __builtin_amdgcn_mfma_f32_16x16x32_bf16(af[f], bh1[f], a1h, 0, 0, 0);
    a0l = __builtin_amdgcn_mfma_f32_16x16x32_bf16(af[f], bl0[f], a0l, 0, 0, 0);
    a1l = __builtin_amdgcn_mfma_f32_16x16x32_bf16(af[f], bl1[f], a1l, 0, 0, 0);
  }

  if (full) {
    const f32x4 dv = *(const f32x4*)(dinv + rb0 + quad * 4);
#pragma unroll
    for (int i = 0; i < 4; ++i) {
      const int r = rb0 + quad * 4 + i;
      out[(size_t)r * 128 + colbase] =
          (unsigned short)bf16_rne((a0h[i] + a0l[i]) * dv[i]);
      out[(size_t)r * 128 + colbase + 16] =
          (unsigned short)bf16_rne((a1h[i] + a1l[i]) * dv[i]);
    }
  } else {
#pragma unroll
    for (int i = 0; i < 4; ++i) {
      const int r = rb0 + quad * 4 + i;
      if (r < M) {
        const float d = dinv[r];
        out[(size_t)r * 128 + colbase] =
            (unsigned short)bf16_rne((a0h[i] + a0l[i]) * d);
        out[(size_t)r * 128 + colbase + 16] =
            (unsigned short)bf16_rne((a1h[i] + a1l[i]) * d);
      }
    }
  }
}

// ---------- FUSED agg1 + gemm2 (unchanged from R20) ----------
__global__ __launch_bounds__(256) void agg_gemm_kernel(
    const unsigned short* __restrict__ xw, const float* __restrict__ dinv,
    const int* __restrict__ rowptr, const int2* __restrict__ csr,
    const float* __restrict__ bias, const short* __restrict__ Wp,
    unsigned short* __restrict__ out, int N) {
  __shared__ short8 z1t[16][16];  // [row][chunk ^ row], 4 KB

  const int tid = threadIdx.x;
  const int node0 = blockIdx.x * 16;
  const int n = tid >> 4;
  const int l = tid & 15;
  const int node = node0 + n;

  short8 o = {0, 0, 0, 0, 0, 0, 0, 0};
  if (node < N) {
    const short8* xw8 = (const short8*)xw;
    short8 sv = xw8[(size_t)node * 16 + l];
    float acc[8];
#pragma unroll
    for (int j = 0; j < 8; ++j) acc[j] = bf2f((unsigned short)sv[j]);
    int s = rowptr[node], e = rowptr[node + 1];
    int k = s;
    for (; k + 4 <= e; k += 4) {
      int j0 = csr[k].x, j1 = csr[k + 1].x, j2 = csr[k + 2].x, j3 = csr[k + 3].x;
      short8 v0 = xw8[(size_t)j0 * 16 + l];
      short8 v1 = xw8[(size_t)j1 * 16 + l];
      short8 v2 = xw8[(size_t)j2 * 16 + l];
      short8 v3 = xw8[(size_t)j3 * 16 + l];
#pragma unroll
      for (int j = 0; j < 8; ++j) {
        acc[j] += (bf2f((unsigned short)v0[j]) + bf2f((unsigned short)v1[j])) +
                  (bf2f((unsigned short)v2[j]) + bf2f((unsigned short)v3[j]));
      }
    }
    for (; k < e; ++k) {
      short8 v = xw8[(size_t)csr[k].x * 16 + l];
#pragma unroll
      for (int j = 0; j < 8; ++j) acc[j] += bf2f((unsigned short)v[j]);
    }
    float di = dinv[node];
    const float4* b4 = (const float4*)bias;
    float4 bb0 = b4[l * 2], bb1 = b4[l * 2 + 1];
    float bv[8] = {bb0.x, bb0.y, bb0.z, bb0.w, bb1.x, bb1.y, bb1.z, bb1.w};
#pragma unroll
    for (int j = 0; j < 8; ++j) {
      float v = fmaf(di, acc[j], bv[j]);
      v = fmaxf(v, 0.f);  // relu (layer 1)
      o[j] = (short)bf16_rne(v);
    }
  }
  z1t[n][l ^ n] = o;  // swizzled store
  __syncthreads();

  const int wave = tid >> 6;
  const int lane = tid & 63;
  const int quad = lane >> 4;
  const int l15 = lane & 15;
  const int ct0 = wave * 2;
  const int ct1 = wave * 2 + 1;

  short8 af[4];
#pragma unroll
  for (int f = 0; f < 4; ++f) af[f] = z1t[l15][(f * 4 + quad) ^ l15];

  const short8* Wp8 = (const short8*)Wp;
  f32x4 a0h = {0.f, 0.f, 0.f, 0.f};
  f32x4 a0l = {0.f, 0.f, 0.f, 0.f};
  f32x4 a1h = {0.f, 0.f, 0.f, 0.f};
  f32x4 a1l = {0.f, 0.f, 0.f, 0.f};
#pragma unroll
  for (int f = 0; f < 4; ++f) {
    const short8 bh0 = Wp8[((0 * 8 + ct0) * 4 + f) * 64 + lane];
    const short8 bh1 = Wp8[((0 * 8 + ct1) * 4 + f) * 64 + lane];
    const short8 bl0 = Wp8[((1 * 8 + ct0) * 4 + f) * 64 + lane];
    const short8 bl1 = Wp8[((1 * 8 + ct1) * 4 + f) * 64 + lane];
    a0h = __builtin_amdgcn_mfma_f32_16x16x32_bf16(af[f], bh0, a0h, 0, 0, 0);
    a1h = __builtin_amdgcn_mfma_f32_16x16x32_bf16(af[f], bh1, a1h, 0, 0, 0);
    a0l = __builtin_amdgcn_mfma_f32_16x16x32_bf16(af[f], bl0, a0l, 0, 0, 0);
    a1l = __builtin_amdgcn_mfma_f32_16x16x32_bf16(af[f], bl1, a1l, 0, 0, 0);
  }

  if (node0 + 16 <= N) {
    const f32x4 dv = *(const f32x4*)(dinv + node0 + quad * 4);
#pragma unroll
    for (int i = 0; i < 4; ++i) {
      const int r = node0 + quad * 4 + i;
      out[(size_t)r * 128 + ct0 * 16 + l15] =
          (unsigned short)bf16_rne((a0h[i] + a0l[i]) * dv[i]);
      out[(size_t)r * 128 + ct1 * 16 + l15] =
          (unsigned short)bf16_rne((a1h[i] + a1l[i]) * dv[i]);
    }
  } else {
#pragma unroll
    for (int i = 0; i < 4; ++i) {
      const int r = node0 + quad * 4 + i;
      if (r < N) {
        const float d = dinv[r];
        out[(size_t)r * 128 + ct0 * 16 + l15] =
            (unsigned short)bf16_rne((a0h[i] + a0l[i]) * d);
        out[(size_t)r * 128 + ct1 * 16 + l15] =
            (unsigned short)bf16_rne((a1h[i] + a1l[i]) * d);
      }
    }
  }
}

// ---------- layer-2 aggregation: 128 thr = 8 nodes/block (tail packing) ----
__global__ __launch_bounds__(128) void agg_kernel(const unsigned short* __restrict__ xw,
                                                  const float* __restrict__ dinv,
                                                  const int* __restrict__ rowptr,
                                                  const int2* __restrict__ csr,
                                                  const float* __restrict__ bias,
                                                  unsigned short* __restrict__ out,
                                                  int relu, int N) {
  int node = blockIdx.x * 8 + (threadIdx.x >> 4);
  int l = threadIdx.x & 15;
  if (node >= N) return;
  const short8* xw8 = (const short8*)xw;
  short8 sv = xw8[(size_t)node * 16 + l];
  float acc[8];
#pragma unroll
  for (int j = 0; j < 8; ++j) acc[j] = bf2f((unsigned short)sv[j]);
  int s = rowptr[node], e = rowptr[node + 1];
  int k = s;
  for (; k + 4 <= e; k += 4) {
    int j0 = csr[k].x, j1 = csr[k + 1].x, j2 = csr[k + 2].x, j3 = csr[k + 3].x;
    short8 v0 = xw8[(size_t)j0 * 16 + l];
    short8 v1 = xw8[(size_t)j1 * 16 + l];
    short8 v2 = xw8[(size_t)j2 * 16 + l];
    short8 v3 = xw8[(size_t)j3 * 16 + l];
#pragma unroll
    for (int j = 0; j < 8; ++j) {
      acc[j] += (bf2f((unsigned short)v0[j]) + bf2f((unsigned short)v1[j])) +
                (bf2f((unsigned short)v2[j]) + bf2f((unsigned short)v3[j]));
    }
  }
  for (; k < e; ++k) {
    short8 v = xw8[(size_t)csr[k].x * 16 + l];
#pragma unroll
    for (int j = 0; j < 8; ++j) acc[j] += bf2f((unsigned short)v[j]);
  }
  float di = dinv[node];
  const float4* b4 = (const float4*)bias;
  float4 bb0 = b4[l * 2], bb1 = b4[l * 2 + 1];
  float bv[8] = {bb0.x, bb0.y, bb0.z, bb0.w, bb1.x, bb1.y, bb1.z, bb1.w};
  short8 o;
#pragma unroll
  for (int j = 0; j < 8; ++j) {
    float v = fmaf(di, acc[j], bv[j]);
    if (relu) v = fmaxf(v, 0.f);
    o[j] = (short)bf16_rne(v);
  }
  ((short8*)out)[(size_t)node * 16 + l] = o;
}

// ---------- decode over dst-CSR: 128 thr = 8 nodes/block ----------
__global__ __launch_bounds__(128) void decode_kernel(const unsigned short* __restrict__ z,
                                                     const int* __restrict__ rowptr,
                                                     const int2* __restrict__ csr,
                                                     float* __restrict__ out, int N) {
  int node = blockIdx.x * 8 + (threadIdx.x >> 4);
  int l = threadIdx.x & 15;
  if (node >= N) return;
  const short8* z8 = (const short8*)z;
  short8 zv = z8[(size_t)node * 16 + l];
  float zd[8];
#pragma unroll
  for (int j = 0; j < 8; ++j) zd[j] = bf2f((unsigned short)zv[j]);
  int s = rowptr[node], e = rowptr[node + 1];
  int k = s;
  for (; k + 4 <= e; k += 4) {
    int2 c0 = csr[k], c1 = csr[k + 1], c2 = csr[k + 2], c3 = csr[k + 3];
    short8 v0 = z8[(size_t)c0.x * 16 + l];
    short8 v1 = z8[(size_t)c1.x * 16 + l];
    short8 v2 = z8[(size_t)c2.x * 16 + l];
    short8 v3 = z8[(size_t)c3.x * 16 + l];
    float p0 = 0.f, p1 = 0.f, p2 = 0.f, p3 = 0.f;
#pragma unroll
    for (int j = 0; j < 8; ++j) {
      p0 = fmaf(zd[j], bf2f((unsigned short)v0[j]), p0);
      p1 = fmaf(zd[j], bf2f((unsigned short)v1[j]), p1);
      p2 = fmaf(zd[j], bf2f((unsigned short)v2[j]), p2);
      p3 = fmaf(zd[j], bf2f((unsigned short)v3[j]), p3);
    }
#pragma unroll
    for (int off = 8; off > 0; off >>= 1) {
      p0 += __shfl_xor(p0, off);
      p1 += __shfl_xor(p1, off);
      p2 += __shfl_xor(p2, off);
      p3 += __shfl_xor(p3, off);
    }
    if (l == 0) {
      out[c0.y] = p0;
      out[c1.y] = p1;
      out[c2.y] = p2;
      out[c3.y] = p3;
    }
  }
  for (; k < e; ++k) {
    int2 c = csr[k];
    short8 v = z8[(size_t)c.x * 16 + l];
    float p = 0.f;
#pragma unroll
    for (int j = 0; j < 8; ++j) p = fmaf(zd[j], bf2f((unsigned short)v[j]), p);
#pragma unroll
    for (int off = 8; off > 0; off >>= 1) p += __shfl_xor(p, off);
    if (l == 0) out[c.y] = p;
  }
}

extern "C" void kernel_launch(void* const* d_in, const int* in_sizes, int n_in,
                              void* d_out, int out_size, void* d_ws, size_t ws_size,
                              hipStream_t stream) {
  const float* x  = (const float*)d_in[0];
  const int*   ei = (const int*)d_in[1];
  const float* W1 = (const float*)d_in[2];
  const float* b1 = (const float*)d_in[3];
  const float* W2 = (const float*)d_in[4];
  const float* b2 = (const float*)d_in[5];

  const int N = in_sizes[0] / 128;
  const int E = in_sizes[1] / 2;
  const int* src = ei;
  const int* dst = ei + E;

  char* ws = (char*)d_ws;
  size_t off = 0;
  auto alloc = [&](size_t bytes) -> void* {
    void* p = ws + off;
    off += (bytes + 255) & ~(size_t)255;
    return p;
  };
  unsigned short* bufA = (unsigned short*)alloc((size_t)N * 128 * 2);
  unsigned short* bufB = (unsigned short*)alloc((size_t)N * 128 * 2);
  float* dinv    = (float*)alloc((size_t)N * 4);
  int*   rowptr  = (int*)alloc((size_t)(N + 1) * 4);
  int2*  csr     = (int2*)alloc((size_t)E * 8);
  short* Wp1     = (short*)alloc((size_t)2 * 8 * 4 * 64 * 8 * 2);
  short* Wp2     = (short*)alloc((size_t)2 * 8 * 4 * 64 * 8 * 2);
  int*   tmp     = (int*)alloc((size_t)N * 4);
  int*   deg     = (int*)alloc((size_t)N * 4);   // zeroed region starts here
  int*   cnt     = (int*)alloc((size_t)N * 4);
  int*   bsums   = (int*)alloc(1024);
  size_t zbytes = ((char*)bsums + 1024) - (char*)deg;
  hipMemsetAsync(deg, 0, zbytes, stream);

  const int E4B = (E + 1023) / 1024;
  const int NB = (N + 255) / 256;
  const int SB = (N + 511) / 512;
  const int G16 = (N + 15) / 16;
  const int AB16 = (N + 15) / 16;
  const int AB8 = (N + 7) / 8;

  // prep: wpack(W1) | wpack(W2) | deg in one dispatch
  prep_kernel<<<16 + E4B, 256, 0, stream>>>(W1, Wp1, W2, Wp2, dst, deg, E);
  scan1_kernel<<<SB, 512, 0, stream>>>(deg, tmp, bsums, N);
  // scan2 folded into scan3
  scan23_kernel<<<NB, 256, 0, stream>>>(tmp, bsums, deg, rowptr, dinv, N, SB);
  // scatter | gemm1 in one dispatch (scatter hides under gemm1 streaming)
  scatgemm_kernel<<<E4B + G16, 256, 0, stream>>>(src, dst, rowptr, cnt, csr, E,
                                                 E4B, x, Wp1, dinv, bufA, N);
  // FUSED: agg layer1 (+b1, relu) -> z1 in LDS -> MFMA z1@W2
  agg_gemm_kernel<<<AB16, 256, 0, stream>>>(bufA, dinv, rowptr, csr, b1, Wp2,
                                            bufB, N);
  // layer 2 aggregation: bufA = z2
  agg_kernel<<<AB8, 128, 0, stream>>>(bufB, dinv, rowptr, csr, b2, bufA, 0, N);
  // decode over dst-CSR
  decode_kernel<<<AB8, 128, 0, stream>>>(bufA, rowptr, csr, (float*)d_out, N);
}

// Round 12
// 259.632 us; speedup vs baseline: 1.3929x; 1.0884x over previous
//
#include <hip/hip_runtime.h>

// GCN link predictor: z1 = relu(GCNConv(x,W1,b1)); z2 = GCNConv(z1,W2,b2);
// out[e] = dot(z2[src[e]], z2[dst[e]])
// R18 WIN (333->313.5): fused gemm2 into agg1 via 4KB LDS z1 tile.
// R19 WIN (313.5->304.2): gemm1 as M=16-tile/block, grid 6250, occ 70%.
// R20 WIN (304.2->292.8): gemm1 LDS A-staging, coalesced loads + swizzle.
// R21 WIN (292.8->282.6): dispatch packing (prep=wpackx2|deg, scan2 folded
//   into scan3, scatter|gemm1 fused, 128-thr agg/decode). BUT scatgemm hit
//   66-68us (gate was 55): WRITE_SIZE 66MB — the 600k cnt-atomicAdd RMW
//   (~38MB line write-through) thrashed L2 against gemm1's x stream.
// R22: delete the scatter atomics, keep the fusion. deg's atomicAdd ALREADY
//   returns each edge's unique slot: store slot[e] in the deg pass (coalesced
//   2.4MB), then scatter = csr[rowptr[d]+slot[e]] = {src,eid} with NO atomic;
//   cnt array + half the memset deleted.

typedef __attribute__((ext_vector_type(8))) short short8;  // 8 bf16 = 4 VGPRs
typedef __attribute__((ext_vector_type(4))) float f32x4;

__device__ __forceinline__ unsigned bf16_rne(float x) {
  unsigned u = __builtin_bit_cast(unsigned, x);
  return (u + 0x7FFFu + ((u >> 16) & 1u)) >> 16;
}
__device__ __forceinline__ float bf2f(unsigned short u) {
  return __builtin_bit_cast(float, ((unsigned)u) << 16);
}

// ---------- wpack body: W[128][128] fp32 -> bf16 hi/lo, MFMA B-frag order --
// B frag (16x16x32): lane holds B[k=(lane>>4)*8+j][n=lane&15], j=0..7.
// Layout: Wp[half(0=hi,1=lo)][ct(8)][kf(4)][lane(64)][8] bf16.
__device__ __forceinline__ void wpack_body(const float* __restrict__ W,
                                           short* __restrict__ Wp, int t) {
  int lane = t & 63;
  int kf = (t >> 6) & 3;
  int ct = t >> 8;
  int col = ct * 16 + (lane & 15);
  int k0 = kf * 32 + (lane >> 4) * 8;
  short* dh = Wp + ((((0 * 8 + ct) * 4 + kf) * 64) + lane) * 8;
  short* dl = Wp + ((((1 * 8 + ct) * 4 + kf) * 64) + lane) * 8;
  for (int j = 0; j < 8; ++j) {
    float w = W[(k0 + j) * 128 + col];
    unsigned h = bf16_rne(w);
    float hf = __builtin_bit_cast(float, h << 16);
    unsigned lo = bf16_rne(w - hf);
    dh[j] = (short)h;
    dl[j] = (short)lo;
  }
}

// ---------- prep: wpack(W1) | wpack(W2) | deg+slot, block-partitioned ------
// deg path: slot[e] = old count — the edge's unique position within its dst
// bucket. The atomic is paid ONCE here; scatter needs no atomic.
__global__ __launch_bounds__(256) void prep_kernel(const float* __restrict__ W1,
                                                   short* __restrict__ Wp1,
                                                   const float* __restrict__ W2,
                                                   short* __restrict__ Wp2,
                                                   const int* __restrict__ dst,
                                                   int* __restrict__ deg,
                                                   int* __restrict__ slot, int E) {
  const int b = blockIdx.x;
  if (b < 8) {
    wpack_body(W1, Wp1, b * 256 + threadIdx.x);
  } else if (b < 16) {
    wpack_body(W2, Wp2, (b - 8) * 256 + threadIdx.x);
  } else {
    int base = (b - 16) * 1024 + threadIdx.x;
#pragma unroll
    for (int i = 0; i < 4; ++i) {
      int e = base + i * 256;
      if (e < E) slot[e] = atomicAdd(&deg[dst[e]], 1);
    }
  }
}

// ---------- block scan (512 elems/block) ----------
__global__ __launch_bounds__(512) void scan1_kernel(const int* __restrict__ in,
                                                    int* __restrict__ tmp,
                                                    int* __restrict__ bsums, int n) {
  __shared__ int sm[2][512];
  int t = threadIdx.x;
  int gid = blockIdx.x * 512 + t;
  int v = (gid < n) ? in[gid] : 0;
  int pp = 0;
  sm[0][t] = v;
  __syncthreads();
  for (int off = 1; off < 512; off <<= 1) {
    int nv = sm[pp][t];
    if (t >= off) nv += sm[pp][t - off];
    sm[pp ^ 1][t] = nv;
    pp ^= 1;
    __syncthreads();
  }
  int inc = sm[pp][t];
  if (gid < n) tmp[gid] = inc;
  if (t == 511) bsums[blockIdx.x] = inc;
}

// ---------- scan2+scan3 merged: each block scans bsums in LDS, then
// rowptr[gid+1] = tmp[gid] + excl_bsums[gid>>9]; dinv fused. nb <= 256. ----
__global__ __launch_bounds__(256) void scan23_kernel(const int* __restrict__ tmp,
                                                     const int* __restrict__ bsums,
                                                     const int* __restrict__ deg,
                                                     int* __restrict__ rowptr,
                                                     float* __restrict__ dinv,
                                                     int n, int nb) {
  __shared__ int sm[2][256];
  __shared__ int orig[256];
  int t = threadIdx.x;
  int v = (t < nb) ? bsums[t] : 0;
  orig[t] = v;
  int pp = 0;
  sm[0][t] = v;
  __syncthreads();
  for (int off = 1; off < 256; off <<= 1) {
    int nv = sm[pp][t];
    if (t >= off) nv += sm[pp][t - off];
    sm[pp ^ 1][t] = nv;
    pp ^= 1;
    __syncthreads();
  }
  int gid = blockIdx.x * 256 + t;
  if (gid < n) {
    int b = gid >> 9;
    rowptr[gid + 1] = tmp[gid] + (sm[pp][b] - orig[b]);  // exclusive offset
    dinv[gid] = rsqrtf((float)(deg[gid] + 1));           // +1 self loop
  }
  if (gid == 0) rowptr[0] = 0;
}

// ---------- scatter(no-atomic) | gemm1 fused dispatch ----------
// Blocks [0, SCB): csr[rowptr[dst[e]] + slot[e]] = {src,eid} — no atomics.
// Blocks [SCB, SCB+G16): layer-1 GEMM, M=16-tile + LDS A-staging (R20 form).
__global__ __launch_bounds__(256, 4) void scatgemm_kernel(
    const int* __restrict__ src, const int* __restrict__ dst,
    const int* __restrict__ rowptr, const int* __restrict__ slot,
    int2* __restrict__ csr, int E, int SCB, const float* __restrict__ A,
    const short* __restrict__ Wp, const float* __restrict__ dinv,
    unsigned short* __restrict__ out, int M) {
  __shared__ short8 lds_a[256];  // 4 KB (gemm path only)

  if ((int)blockIdx.x < SCB) {
    // ---- scatter path (atomic-free) ----
    int base = blockIdx.x * 1024 + threadIdx.x;
#pragma unroll
    for (int i = 0; i < 4; ++i) {
      int e = base + i * 256;
      if (e < E) {
        int d = dst[e];
        csr[rowptr[d] + slot[e]] = make_int2(src[e], e);
      }
    }
    return;
  }

  // ---- gemm1 path (R20: coalesced stage -> swizzled LDS -> MFMA) ----
  const int bid = blockIdx.x - SCB;
  const int tid = threadIdx.x;
  const int wave = tid >> 6;
  const int lane = tid & 63;
  const int quad = lane >> 4;
  const int l15 = lane & 15;
  const int ct0 = wave * 2;
  const int ct1 = wave * 2 + 1;
  const int colbase = wave * 32 + l15;
  const int rb0 = bid * 16;
  const bool full = (rb0 + 16 <= M);
  const short8* Wp8 = (const short8*)Wp;

  {
    const int row = tid >> 4;
    const int seg = tid & 15;
    float4 a0 = {0.f, 0.f, 0.f, 0.f}, a1 = {0.f, 0.f, 0.f, 0.f};
    if (full || rb0 + row < M) {
      const float4* p = (const float4*)A + (size_t)(rb0 + row) * 32 + seg * 2;
      a0 = p[0];
      a1 = p[1];
    }
    const float av[8] = {a0.x, a0.y, a0.z, a0.w, a1.x, a1.y, a1.z, a1.w};
    short8 w;
#pragma unroll
    for (int j = 0; j < 8; ++j) w[j] = (short)bf16_rne(av[j]);
    lds_a[row * 16 + (seg ^ (row & 7))] = w;
  }

  // B frags issued BEFORE the barrier (barrier pins them; overlap staging)
  short8 bh0[4], bh1[4], bl0[4], bl1[4];
#pragma unroll
  for (int f = 0; f < 4; ++f) {
    bh0[f] = Wp8[((0 * 8 + ct0) * 4 + f) * 64 + lane];
    bh1[f] = Wp8[((0 * 8 + ct1) * 4 + f) * 64 + lane];
    bl0[f] = Wp8[((1 * 8 + ct0) * 4 + f) * 64 + lane];
    bl1[f] = Wp8[((1 * 8 + ct1) * 4 + f) * 64 + lane];
  }

  __syncthreads();

  short8 af[4];
#pragma unroll
  for (int f = 0; f < 4; ++f) af[f] = lds_a[l15 * 16 + ((f * 4 + quad) ^ (l15 & 7))];

  f32x4 a0h = {0.f, 0.f, 0.f, 0.f};
  f32x4 a0l = {0.f, 0.f, 0.f, 0.f};
  f32x4 a1h = {0.f, 0.f, 0.f, 0.f};
  f32x4 a1l = {0.f, 0.f, 0.f, 0.f};
#pragma unroll
  for (int f = 0; f < 4; ++f) {
    a0h = __builtin_amdgcn_mfma_f32_16x16x32_bf16(af[f], bh0[f], a0h, 0, 0, 0);
    a1h = __builtin_amdgcn_mfma_f32_16x16x32_bf16(af[f], bh1[f], a1h, 0, 0, 0);
    a0l = __builtin_amdgcn_mfma_f32_16x16x32_bf16(af[f], bl0[f], a0l, 0, 0, 0);
    a1l = __builtin_amdgcn_mfma_f32_16x16x32_bf16(af[f], bl1[f], a1l, 0, 0, 0);
  }

  if (full) {
    const f32x4 dv = *(const f32x4*)(dinv + rb0 + quad * 4);
#pragma unroll
    for (int i = 0; i < 4; ++i) {
      const int r = rb0 + quad * 4 + i;
      out[(size_t)r * 128 + colbase] =
          (unsigned short)bf16_rne((a0h[i] + a0l[i]) * dv[i]);
      out[(size_t)r * 128 + colbase + 16] =
          (unsigned short)bf16_rne((a1h[i] + a1l[i]) * dv[i]);
    }
  } else {
#pragma unroll
    for (int i = 0; i < 4; ++i) {
      const int r = rb0 + quad * 4 + i;
      if (r < M) {
        const float d = dinv[r];
        out[(size_t)r * 128 + colbase] =
            (unsigned short)bf16_rne((a0h[i] + a0l[i]) * d);
        out[(size_t)r * 128 + colbase + 16] =
            (unsigned short)bf16_rne((a1h[i] + a1l[i]) * d);
      }
    }
  }
}

// ---------- FUSED agg1 + gemm2 (unchanged) ----------
__global__ __launch_bounds__(256) void agg_gemm_kernel(
    const unsigned short* __restrict__ xw, const float* __restrict__ dinv,
    const int* __restrict__ rowptr, const int2* __restrict__ csr,
    const float* __restrict__ bias, const short* __restrict__ Wp,
    unsigned short* __restrict__ out, int N) {
  __shared__ short8 z1t[16][16];  // [row][chunk ^ row], 4 KB

  const int tid = threadIdx.x;
  const int node0 = blockIdx.x * 16;
  const int n = tid >> 4;
  const int l = tid & 15;
  const int node = node0 + n;

  short8 o = {0, 0, 0, 0, 0, 0, 0, 0};
  if (node < N) {
    const short8* xw8 = (const short8*)xw;
    short8 sv = xw8[(size_t)node * 16 + l];
    float acc[8];
#pragma unroll
    for (int j = 0; j < 8; ++j) acc[j] = bf2f((unsigned short)sv[j]);
    int s = rowptr[node], e = rowptr[node + 1];
    int k = s;
    for (; k + 4 <= e; k += 4) {
      int j0 = csr[k].x, j1 = csr[k + 1].x, j2 = csr[k + 2].x, j3 = csr[k + 3].x;
      short8 v0 = xw8[(size_t)j0 * 16 + l];
      short8 v1 = xw8[(size_t)j1 * 16 + l];
      short8 v2 = xw8[(size_t)j2 * 16 + l];
      short8 v3 = xw8[(size_t)j3 * 16 + l];
#pragma unroll
      for (int j = 0; j < 8; ++j) {
        acc[j] += (bf2f((unsigned short)v0[j]) + bf2f((unsigned short)v1[j])) +
                  (bf2f((unsigned short)v2[j]) + bf2f((unsigned short)v3[j]));
      }
    }
    for (; k < e; ++k) {
      short8 v = xw8[(size_t)csr[k].x * 16 + l];
#pragma unroll
      for (int j = 0; j < 8; ++j) acc[j] += bf2f((unsigned short)v[j]);
    }
    float di = dinv[node];
    const float4* b4 = (const float4*)bias;
    float4 bb0 = b4[l * 2], bb1 = b4[l * 2 + 1];
    float bv[8] = {bb0.x, bb0.y, bb0.z, bb0.w, bb1.x, bb1.y, bb1.z, bb1.w};
#pragma unroll
    for (int j = 0; j < 8; ++j) {
      float v = fmaf(di, acc[j], bv[j]);
      v = fmaxf(v, 0.f);  // relu (layer 1)
      o[j] = (short)bf16_rne(v);
    }
  }
  z1t[n][l ^ n] = o;  // swizzled store
  __syncthreads();

  const int wave = tid >> 6;
  const int lane = tid & 63;
  const int quad = lane >> 4;
  const int l15 = lane & 15;
  const int ct0 = wave * 2;
  const int ct1 = wave * 2 + 1;

  short8 af[4];
#pragma unroll
  for (int f = 0; f < 4; ++f) af[f] = z1t[l15][(f * 4 + quad) ^ l15];

  const short8* Wp8 = (const short8*)Wp;
  f32x4 a0h = {0.f, 0.f, 0.f, 0.f};
  f32x4 a0l = {0.f, 0.f, 0.f, 0.f};
  f32x4 a1h = {0.f, 0.f, 0.f, 0.f};
  f32x4 a1l = {0.f, 0.f, 0.f, 0.f};
#pragma unroll
  for (int f = 0; f < 4; ++f) {
    const short8 bh0 = Wp8[((0 * 8 + ct0) * 4 + f) * 64 + lane];
    const short8 bh1 = Wp8[((0 * 8 + ct1) * 4 + f) * 64 + lane];
    const short8 bl0 = Wp8[((1 * 8 + ct0) * 4 + f) * 64 + lane];
    const short8 bl1 = Wp8[((1 * 8 + ct1) * 4 + f) * 64 + lane];
    a0h = __builtin_amdgcn_mfma_f32_16x16x32_bf16(af[f], bh0, a0h, 0, 0, 0);
    a1h = __builtin_amdgcn_mfma_f32_16x16x32_bf16(af[f], bh1, a1h, 0, 0, 0);
    a0l = __builtin_amdgcn_mfma_f32_16x16x32_bf16(af[f], bl0, a0l, 0, 0, 0);
    a1l = __builtin_amdgcn_mfma_f32_16x16x32_bf16(af[f], bl1, a1l, 0, 0, 0);
  }

  if (node0 + 16 <= N) {
    const f32x4 dv = *(const f32x4*)(dinv + node0 + quad * 4);
#pragma unroll
    for (int i = 0; i < 4; ++i) {
      const int r = node0 + quad * 4 + i;
      out[(size_t)r * 128 + ct0 * 16 + l15] =
          (unsigned short)bf16_rne((a0h[i] + a0l[i]) * dv[i]);
      out[(size_t)r * 128 + ct1 * 16 + l15] =
          (unsigned short)bf16_rne((a1h[i] + a1l[i]) * dv[i]);
    }
  } else {
#pragma unroll
    for (int i = 0; i < 4; ++i) {
      const int r = node0 + quad * 4 + i;
      if (r < N) {
        const float d = dinv[r];
        out[(size_t)r * 128 + ct0 * 16 + l15] =
            (unsigned short)bf16_rne((a0h[i] + a0l[i]) * d);
        out[(size_t)r * 128 + ct1 * 16 + l15] =
            (unsigned short)bf16_rne((a1h[i] + a1l[i]) * d);
      }
    }
  }
}

// ---------- layer-2 aggregation: 128 thr = 8 nodes/block (tail packing) ----
__global__ __launch_bounds__(128) void agg_kernel(const unsigned short* __restrict__ xw,
                                                  const float* __restrict__ dinv,
                                                  const int* __restrict__ rowptr,
                                                  const int2* __restrict__ csr,
                                                  const float* __restrict__ bias,
                                                  unsigned short* __restrict__ out,
                                                  int relu, int N) {
  int node = blockIdx.x * 8 + (threadIdx.x >> 4);
  int l = threadIdx.x & 15;
  if (node >= N) return;
  const short8* xw8 = (const short8*)xw;
  short8 sv = xw8[(size_t)node * 16 + l];
  float acc[8];
#pragma unroll
  for (int j = 0; j < 8; ++j) acc[j] = bf2f((unsigned short)sv[j]);
  int s = rowptr[node], e = rowptr[node + 1];
  int k = s;
  for (; k + 4 <= e; k += 4) {
    int j0 = csr[k].x, j1 = csr[k + 1].x, j2 = csr[k + 2].x, j3 = csr[k + 3].x;
    short8 v0 = xw8[(size_t)j0 * 16 + l];
    short8 v1 = xw8[(size_t)j1 * 16 + l];
    short8 v2 = xw8[(size_t)j2 * 16 + l];
    short8 v3 = xw8[(size_t)j3 * 16 + l];
#pragma unroll
    for (int j = 0; j < 8; ++j) {
      acc[j] += (bf2f((unsigned short)v0[j]) + bf2f((unsigned short)v1[j])) +
                (bf2f((unsigned short)v2[j]) + bf2f((unsigned short)v3[j]));
    }
  }
  for (; k < e; ++k) {
    short8 v = xw8[(size_t)csr[k].x * 16 + l];
#pragma unroll
    for (int j = 0; j < 8; ++j) acc[j] += bf2f((unsigned short)v[j]);
  }
  float di = dinv[node];
  const float4* b4 = (const float4*)bias;
  float4 bb0 = b4[l * 2], bb1 = b4[l * 2 + 1];
  float bv[8] = {bb0.x, bb0.y, bb0.z, bb0.w, bb1.x, bb1.y, bb1.z, bb1.w};
  short8 o;
#pragma unroll
  for (int j = 0; j < 8; ++j) {
    float v = fmaf(di, acc[j], bv[j]);
    if (relu) v = fmaxf(v, 0.f);
    o[j] = (short)bf16_rne(v);
  }
  ((short8*)out)[(size_t)node * 16 + l] = o;
}

// ---------- decode over dst-CSR: 128 thr = 8 nodes/block ----------
__global__ __launch_bounds__(128) void decode_kernel(const unsigned short* __restrict__ z,
                                                     const int* __restrict__ rowptr,
                                                     const int2* __restrict__ csr,
                                                     float* __restrict__ out, int N) {
  int node = blockIdx.x * 8 + (threadIdx.x >> 4);
  int l = threadIdx.x & 15;
  if (node >= N) return;
  const short8* z8 = (const short8*)z;
  short8 zv = z8[(size_t)node * 16 + l];
  float zd[8];
#pragma unroll
  for (int j = 0; j < 8; ++j) zd[j] = bf2f((unsigned short)zv[j]);
  int s = rowptr[node], e = rowptr[node + 1];
  int k = s;
  for (; k + 4 <= e; k += 4) {
    int2 c0 = csr[k], c1 = csr[k + 1], c2 = csr[k + 2], c3 = csr[k + 3];
    short8 v0 = z8[(size_t)c0.x * 16 + l];
    short8 v1 = z8[(size_t)c1.x * 16 + l];
    short8 v2 = z8[(size_t)c2.x * 16 + l];
    short8 v3 = z8[(size_t)c3.x * 16 + l];
    float p0 = 0.f, p1 = 0.f, p2 = 0.f, p3 = 0.f;
#pragma unroll
    for (int j = 0; j < 8; ++j) {
      p0 = fmaf(zd[j], bf2f((unsigned short)v0[j]), p0);
      p1 = fmaf(zd[j], bf2f((unsigned short)v1[j]), p1);
      p2 = fmaf(zd[j], bf2f((unsigned short)v2[j]), p2);
      p3 = fmaf(zd[j], bf2f((unsigned short)v3[j]), p3);
    }
#pragma unroll
    for (int off = 8; off > 0; off >>= 1) {
      p0 += __shfl_xor(p0, off);
      p1 += __shfl_xor(p1, off);
      p2 += __shfl_xor(p2, off);
      p3 += __shfl_xor(p3, off);
    }
    if (l == 0) {
      out[c0.y] = p0;
      out[c1.y] = p1;
      out[c2.y] = p2;
      out[c3.y] = p3;
    }
  }
  for (; k < e; ++k) {
    int2 c = csr[k];
    short8 v = z8[(size_t)c.x * 16 + l];
    float p = 0.f;
#pragma unroll
    for (int j = 0; j < 8; ++j) p = fmaf(zd[j], bf2f((unsigned short)v[j]), p);
#pragma unroll
    for (int off = 8; off > 0; off >>= 1) p += __shfl_xor(p, off);
    if (l == 0) out[c.y] = p;
  }
}

extern "C" void kernel_launch(void* const* d_in, const int* in_sizes, int n_in,
                              void* d_out, int out_size, void* d_ws, size_t ws_size,
                              hipStream_t stream) {
  const float* x  = (const float*)d_in[0];
  const int*   ei = (const int*)d_in[1];
  const float* W1 = (const float*)d_in[2];
  const float* b1 = (const float*)d_in[3];
  const float* W2 = (const float*)d_in[4];
  const float* b2 = (const float*)d_in[5];

  const int N = in_sizes[0] / 128;
  const int E = in_sizes[1] / 2;
  const int* src = ei;
  const int* dst = ei + E;

  char* ws = (char*)d_ws;
  size_t off = 0;
  auto alloc = [&](size_t bytes) -> void* {
    void* p = ws + off;
    off += (bytes + 255) & ~(size_t)255;
    return p;
  };
  unsigned short* bufA = (unsigned short*)alloc((size_t)N * 128 * 2);
  unsigned short* bufB = (unsigned short*)alloc((size_t)N * 128 * 2);
  float* dinv    = (float*)alloc((size_t)N * 4);
  int*   rowptr  = (int*)alloc((size_t)(N + 1) * 4);
  int2*  csr     = (int2*)alloc((size_t)E * 8);
  short* Wp1     = (short*)alloc((size_t)2 * 8 * 4 * 64 * 8 * 2);
  short* Wp2     = (short*)alloc((size_t)2 * 8 * 4 * 64 * 8 * 2);
  int*   tmp     = (int*)alloc((size_t)N * 4);
  int*   slot    = (int*)alloc((size_t)E * 4);
  int*   deg     = (int*)alloc((size_t)N * 4);   // zeroed region starts here
  int*   bsums   = (int*)alloc(1024);
  size_t zbytes = ((char*)bsums + 1024) - (char*)deg;
  hipMemsetAsync(deg, 0, zbytes, stream);

  const int E4B = (E + 1023) / 1024;
  const int NB = (N + 255) / 256;
  const int SB = (N + 511) / 512;
  const int G16 = (N + 15) / 16;
  const int AB16 = (N + 15) / 16;
  const int AB8 = (N + 7) / 8;

  // prep: wpack(W1) | wpack(W2) | deg+slot in one dispatch
  prep_kernel<<<16 + E4B, 256, 0, stream>>>(W1, Wp1, W2, Wp2, dst, deg, slot, E);
  scan1_kernel<<<SB, 512, 0, stream>>>(deg, tmp, bsums, N);
  // scan2 folded into scan3
  scan23_kernel<<<NB, 256, 0, stream>>>(tmp, bsums, deg, rowptr, dinv, N, SB);
  // scatter(no-atomic) | gemm1 in one dispatch
  scatgemm_kernel<<<E4B + G16, 256, 0, stream>>>(src, dst, rowptr, slot, csr, E,
                                                 E4B, x, Wp1, dinv, bufA, N);
  // FUSED: agg layer1 (+b1, relu) -> z1 in LDS -> MFMA z1@W2
  agg_gemm_kernel<<<AB16, 256, 0, stream>>>(bufA, dinv, rowptr, csr, b1, Wp2,
                                            bufB, N);
  // layer 2 aggregation: bufA = z2
  agg_kernel<<<AB8, 128, 0, stream>>>(bufB, dinv, rowptr, csr, b2, bufA, 0, N);
  // decode over dst-CSR
  decode_kernel<<<AB8, 128, 0, stream>>>(bufA, rowptr, csr, (float*)d_out, N);
}